// Round 1
// baseline (1676.341 us; speedup 1.0000x reference)
//
#include <hip/hip_runtime.h>
#include <hip/hip_bf16.h>
#include <stdint.h>

#define BATCH 2
#define CH 256
#define NSP 4096          // 64*64 spatial
#define HEADS 8
#define HD 32
#define GROUPS 32
#define EPS_GN 1e-5f

typedef __attribute__((ext_vector_type(8))) short short8;   // 8 bf16 = 4 VGPR (MFMA A/B frag)
typedef __attribute__((ext_vector_type(4))) float f32x4;    // MFMA C/D frag

static __device__ __forceinline__ unsigned short f2bf(float f) {
    union { float f; unsigned u; } v; v.f = f;
    unsigned r = v.u + 0x7fffu + ((v.u >> 16) & 1u);  // RNE
    return (unsigned short)(r >> 16);
}

// ---------------- K1: GroupNorm stats: one block per (b,group) ----------------
__global__ void k_gnstats(const float* __restrict__ x, float* __restrict__ stats) {
    int bg = blockIdx.x;              // b*32+g ; channels are contiguous: base = bg*8*4096
    int t = threadIdx.x;
    const float4* b4 = (const float4*)(x + (size_t)bg * (8 * NSP));
    float s = 0.f, sq = 0.f;
    #pragma unroll
    for (int i = 0; i < 32; i++) {
        float4 v = b4[t + i * 256];
        s  += v.x + v.y + v.z + v.w;
        sq += v.x * v.x + v.y * v.y + v.z * v.z + v.w * v.w;
    }
    #pragma unroll
    for (int off = 32; off > 0; off >>= 1) {
        s  += __shfl_down(s, off);
        sq += __shfl_down(sq, off);
    }
    __shared__ float rs[4], rq[4];
    int w = t >> 6;
    if ((t & 63) == 0) { rs[w] = s; rq[w] = sq; }
    __syncthreads();
    if (t == 0) {
        float S = rs[0] + rs[1] + rs[2] + rs[3];
        float Q = rq[0] + rq[1] + rq[2] + rq[3];
        float mu  = S * (1.0f / 32768.0f);
        float var = Q * (1.0f / 32768.0f) - mu * mu;
        stats[bg * 2]     = mu;
        stats[bg * 2 + 1] = rsqrtf(var + EPS_GN);
    }
}

// ------ K2: apply GN, write xn^T (b,p,c) bf16, per-channel partial sums ------
__global__ void k_gnapply(const float* __restrict__ x, const float* __restrict__ gn_w,
                          const float* __restrict__ gn_b, const float* __restrict__ stats,
                          unsigned short* __restrict__ xnt, float* __restrict__ gpart) {
    int p0 = blockIdx.x * 64, c0 = blockIdx.y * 64, b = blockIdx.z;
    int t = threadIdx.x;
    __shared__ float tile[64][65];    // [c_local][p_local], +1 pad
    int ci0 = t >> 4, pq = t & 15;
    #pragma unroll
    for (int k = 0; k < 4; k++) {
        int ci = ci0 + k * 16;
        int c = c0 + ci;
        float mu   = stats[(b * GROUPS + (c >> 3)) * 2];
        float rstd = stats[(b * GROUPS + (c >> 3)) * 2 + 1];
        float w  = gn_w[c] * rstd;
        float bb = gn_b[c] - mu * w;          // xn = x*w + bb
        float4 v = *(const float4*)(x + ((size_t)(b * CH + c)) * NSP + p0 + pq * 4);
        tile[ci][pq * 4 + 0] = v.x * w + bb;
        tile[ci][pq * 4 + 1] = v.y * w + bb;
        tile[ci][pq * 4 + 2] = v.z * w + bb;
        tile[ci][pq * 4 + 3] = v.w * w + bb;
    }
    __syncthreads();
    // transposed bf16 write: 16 contiguous c per thread
    int pi = t >> 2, cb = (t & 3) * 16;
    unsigned pack[8];
    #pragma unroll
    for (int e = 0; e < 8; e++) {
        float a  = tile[cb + 2 * e][pi];
        float bv = tile[cb + 2 * e + 1][pi];
        pack[e] = (unsigned)f2bf(a) | ((unsigned)f2bf(bv) << 16);
    }
    uint4* dst = (uint4*)(xnt + ((size_t)(b * NSP + p0 + pi)) * CH + c0 + cb);
    dst[0] = make_uint4(pack[0], pack[1], pack[2], pack[3]);
    dst[1] = make_uint4(pack[4], pack[5], pack[6], pack[7]);
    // per-channel partial sums (fp32, pre-rounding) for gfeat
    if (t < 64) {
        float s = 0.f;
        #pragma unroll
        for (int j = 0; j < 64; j++) s += tile[t][j];
        gpart[((size_t)(b * CH + c0 + t)) * 64 + blockIdx.x] = s;
    }
}

// -------- K3: gfeat = mean(xn) @ gproj_w^T + gproj_b  (one block per b) --------
__global__ void k_gproj(const float* __restrict__ gpart, const float* __restrict__ gproj_w,
                        const float* __restrict__ gproj_b, float* __restrict__ gfeat) {
    int b = blockIdx.x, t = threadIdx.x;
    __shared__ float graw[256];
    const float* p = gpart + ((size_t)(b * CH + t)) * 64;
    float s = 0.f;
    #pragma unroll
    for (int i = 0; i < 64; i++) s += p[i];
    graw[t] = s * (1.0f / 4096.0f);
    __syncthreads();
    float acc = gproj_b[t];
    const float* wr = gproj_w + (size_t)t * CH;
    #pragma unroll 8
    for (int c = 0; c < 256; c++) acc += graw[c] * wr[c];
    gfeat[b * CH + t] = acc;
}

// ---------------- K4: convert qkv_w + proj_w to bf16 (contiguous) ----------------
__global__ void k_convert(const float* __restrict__ qkv_w, const float* __restrict__ proj_w,
                          unsigned short* __restrict__ wbf) {
    int i4 = blockIdx.x * 256 + threadIdx.x;   // 65536 float4s total
    const float* src = (i4 < 49152) ? (qkv_w + (size_t)i4 * 4)
                                    : (proj_w + (size_t)(i4 - 49152) * 4);
    float4 v = *(const float4*)src;
    ushort4 o;
    o.x = f2bf(v.x); o.y = f2bf(v.y); o.z = f2bf(v.z); o.w = f2bf(v.w);
    *(ushort4*)(wbf + (size_t)i4 * 4) = o;
}

// ---------------- K5: bf16 MFMA GEMM, 64x128 tile, K=256 ----------------
// A: M x 256 row-major bf16.  B given transposed: (4096 x 256) per batch, row-major.
// MODE 0: qkv (M=768), out fp32 qkvbuf; k-rows (256..511) get +0.1*gfeat
// MODE 1: proj (M=256), out fp32 d_out; add proj_b + 0.1*gfeat + x residual
template<int MODE>
__global__ void k_gemm(const unsigned short* __restrict__ Ag,
                       const unsigned short* __restrict__ Btg,
                       const float* __restrict__ bias,
                       const float* __restrict__ gfeat,
                       const float* __restrict__ xres,
                       float* __restrict__ out) {
    int n0 = blockIdx.x * 128, m0 = blockIdx.y * 64, b = blockIdx.z;
    int t = threadIdx.x, lane = t & 63, w = t >> 6;
    int wm = w >> 1, wn = w & 1;
    __shared__ short A_lds[64][40];    // padded stride 40 (bank-friendly)
    __shared__ short B_lds[128][40];
    const unsigned short* Bb = Btg + (size_t)b * NSP * CH;
    f32x4 acc[2][4];
    #pragma unroll
    for (int m = 0; m < 2; m++)
        #pragma unroll
        for (int n = 0; n < 4; n++) acc[m][n] = (f32x4){0.f, 0.f, 0.f, 0.f};
    int arow = t >> 2, akk = (t & 3) * 8;
    for (int k0 = 0; k0 < 256; k0 += 32) {
        __syncthreads();
        *(uint4*)&A_lds[arow][akk] = *(const uint4*)(Ag + (size_t)(m0 + arow) * CH + k0 + akk);
        #pragma unroll
        for (int hh = 0; hh < 2; hh++) {
            int f = t + hh * 256;
            int j = f >> 2, kk = (f & 3) * 8;
            *(uint4*)&B_lds[j][kk] = *(const uint4*)(Bb + (size_t)(n0 + j) * CH + k0 + kk);
        }
        __syncthreads();
        short8 a[2], bf[4];
        #pragma unroll
        for (int m = 0; m < 2; m++)
            a[m] = *(const short8*)&A_lds[wm * 32 + m * 16 + (lane & 15)][(lane >> 4) * 8];
        #pragma unroll
        for (int n = 0; n < 4; n++)
            bf[n] = *(const short8*)&B_lds[wn * 64 + n * 16 + (lane & 15)][(lane >> 4) * 8];
        #pragma unroll
        for (int m = 0; m < 2; m++)
            #pragma unroll
            for (int n = 0; n < 4; n++)
                acc[m][n] = __builtin_amdgcn_mfma_f32_16x16x32_bf16(a[m], bf[n], acc[m][n], 0, 0, 0);
    }
    int rbase = m0 + wm * 32 + ((lane >> 4) << 2);
    int cbase = n0 + wn * 64 + (lane & 15);
    #pragma unroll
    for (int m = 0; m < 2; m++) {
        #pragma unroll
        for (int n = 0; n < 4; n++) {
            int col = cbase + n * 16;
            #pragma unroll
            for (int i = 0; i < 4; i++) {
                int row = rbase + m * 16 + i;
                float v = acc[m][n][i];
                if (MODE == 0) {
                    float add = bias[row];
                    if (row >= 256 && row < 512) add += 0.1f * gfeat[b * CH + row - 256];
                    out[((size_t)(b * 768 + row)) * NSP + col] = v + add;
                } else {
                    float add = bias[row] + 0.1f * gfeat[b * CH + row]
                              + xres[((size_t)(b * CH + row)) * NSP + col];
                    out[((size_t)(b * CH + row)) * NSP + col] = v + add;
                }
            }
        }
    }
}

// ------------- K6: fp32 flash attention, 1 thread = 1 q-row -------------
__global__ __launch_bounds__(128)
void k_flash(const float* __restrict__ qkv, unsigned short* __restrict__ att) {
    int qt = blockIdx.x, h = blockIdx.y, b = blockIdx.z;
    int t = threadIdx.x;
    int r = qt * 128 + t;
    const float* qp = qkv + ((size_t)(b * 768) + h * HD) * NSP;
    const float* kp = qkv + ((size_t)(b * 768) + 256 + h * HD) * NSP;
    const float* vp = qkv + ((size_t)(b * 768) + 512 + h * HD) * NSP;
    __shared__ float K_lds[32][128];
    __shared__ float V_lds[32][128];
    float q[32], o[32];
    const float scale = 0.17677669529663687f;   // hd^-0.5, folded into q
    #pragma unroll
    for (int d = 0; d < 32; d++) { q[d] = qp[(size_t)d * NSP + r] * scale; o[d] = 0.f; }
    float mx = -1e30f, l = 0.f;
    for (int kt = 0; kt < 32; kt++) {
        int j0 = kt * 128;
        __syncthreads();
        #pragma unroll
        for (int i = 0; i < 8; i++) {
            int f = t + i * 128;
            int d = f >> 5, j4 = (f & 31);
            *(float4*)&K_lds[d][j4 * 4] = *(const float4*)(kp + (size_t)d * NSP + j0 + j4 * 4);
            *(float4*)&V_lds[d][j4 * 4] = *(const float4*)(vp + (size_t)d * NSP + j0 + j4 * 4);
        }
        __syncthreads();
        #pragma unroll 1
        for (int cc = 0; cc < 8; cc++) {
            float s[16];
            #pragma unroll
            for (int jj = 0; jj < 16; jj++) s[jj] = 0.f;
            #pragma unroll
            for (int d = 0; d < 32; d++) {
                const float4* kr = (const float4*)&K_lds[d][cc * 16];  // uniform addr: broadcast
                float4 k0 = kr[0], k1 = kr[1], k2 = kr[2], k3 = kr[3];
                float qd = q[d];
                s[0] += qd * k0.x;  s[1] += qd * k0.y;  s[2] += qd * k0.z;  s[3] += qd * k0.w;
                s[4] += qd * k1.x;  s[5] += qd * k1.y;  s[6] += qd * k1.z;  s[7] += qd * k1.w;
                s[8] += qd * k2.x;  s[9] += qd * k2.y;  s[10] += qd * k2.z; s[11] += qd * k2.w;
                s[12] += qd * k3.x; s[13] += qd * k3.y; s[14] += qd * k3.z; s[15] += qd * k3.w;
            }
            float cm = s[0];
            #pragma unroll
            for (int jj = 1; jj < 16; jj++) cm = fmaxf(cm, s[jj]);
            float nm = fmaxf(mx, cm);
            float corr = __expf(mx - nm);   // -1e30 first time -> 0, safe
            l *= corr;
            #pragma unroll
            for (int d = 0; d < 32; d++) o[d] *= corr;
            #pragma unroll
            for (int jj = 0; jj < 16; jj++) { s[jj] = __expf(s[jj] - nm); l += s[jj]; }
            #pragma unroll
            for (int d = 0; d < 32; d++) {
                const float4* vr = (const float4*)&V_lds[d][cc * 16];
                float4 v0 = vr[0], v1 = vr[1], v2 = vr[2], v3 = vr[3];
                float t0 = s[0] * v0.x + s[1] * v0.y;
                float t1 = s[2] * v0.z + s[3] * v0.w;
                float t2 = s[4] * v1.x + s[5] * v1.y;
                float t3 = s[6] * v1.z + s[7] * v1.w;
                float t4 = s[8] * v2.x + s[9] * v2.y;
                float t5 = s[10] * v2.z + s[11] * v2.w;
                float t6 = s[12] * v3.x + s[13] * v3.y;
                float t7 = s[14] * v3.z + s[15] * v3.w;
                o[d] += ((t0 + t1) + (t2 + t3)) + ((t4 + t5) + (t6 + t7));
            }
            mx = nm;
        }
    }
    float inv = 1.0f / l;
    unsigned pack[16];
    #pragma unroll
    for (int e = 0; e < 16; e++)
        pack[e] = (unsigned)f2bf(o[2 * e] * inv) | ((unsigned)f2bf(o[2 * e + 1] * inv) << 16);
    // att^T layout (b, p, c): 64B contiguous per thread
    uint4* dst = (uint4*)(att + ((size_t)(b * NSP + r)) * CH + h * HD);
    #pragma unroll
    for (int e = 0; e < 4; e++)
        dst[e] = make_uint4(pack[4 * e], pack[4 * e + 1], pack[4 * e + 2], pack[4 * e + 3]);
}

extern "C" void kernel_launch(void* const* d_in, const int* in_sizes, int n_in,
                              void* d_out, int out_size, void* d_ws, size_t ws_size,
                              hipStream_t stream) {
    const float* x       = (const float*)d_in[0];
    const float* gn_w    = (const float*)d_in[1];
    const float* gn_b    = (const float*)d_in[2];
    const float* qkv_w   = (const float*)d_in[3];
    const float* qkv_b   = (const float*)d_in[4];
    const float* proj_w  = (const float*)d_in[5];
    const float* proj_b  = (const float*)d_in[6];
    const float* gproj_w = (const float*)d_in[7];
    const float* gproj_b = (const float*)d_in[8];
    char* ws = (char*)d_ws;
    // workspace layout (bytes), all 256B-aligned; total ~34.2 MB
    float*          stats  = (float*)(ws);                       // 512 B
    float*          gpart  = (float*)(ws + 1024);                // 2*256*64*4 = 128 KB
    float*          gfeat  = (float*)(ws + 132096);              // 2 KB
    unsigned short* wbf    = (unsigned short*)(ws + 134144);     // qkv_w(196608) + proj_w(65536) bf16
    unsigned short* xnt    = (unsigned short*)(ws + 658432);     // (b,p,c) bf16, 4 MB
    float*          qkvbuf = (float*)(ws + 4852736);             // (b,768,4096) fp32, 24 MB
    unsigned short* att    = (unsigned short*)(ws + 30018560);   // (b,p,c) bf16, 4 MB
    float* out = (float*)d_out;

    hipLaunchKernelGGL(k_gnstats, dim3(64), dim3(256), 0, stream, x, stats);
    hipLaunchKernelGGL(k_gnapply, dim3(64, 4, 2), dim3(256), 0, stream,
                       x, gn_w, gn_b, stats, xnt, gpart);
    hipLaunchKernelGGL(k_gproj, dim3(2), dim3(256), 0, stream,
                       gpart, gproj_w, gproj_b, gfeat);
    hipLaunchKernelGGL(k_convert, dim3(256), dim3(256), 0, stream, qkv_w, proj_w, wbf);
    hipLaunchKernelGGL((k_gemm<0>), dim3(32, 12, 2), dim3(256), 0, stream,
                       wbf, xnt, qkv_b, gfeat, (const float*)nullptr, qkvbuf);
    hipLaunchKernelGGL(k_flash, dim3(32, 8, 2), dim3(128), 0, stream, qkvbuf, att);
    hipLaunchKernelGGL((k_gemm<1>), dim3(32, 4, 2), dim3(256), 0, stream,
                       wbf + 196608, att, proj_b, gfeat, x, out);
}

// Round 2
// 242.169 us; speedup vs baseline: 6.9222x; 6.9222x over previous
//
#include <hip/hip_runtime.h>
#include <hip/hip_bf16.h>
#include <stdint.h>

#define BATCH 2
#define CH 256
#define NSP 4096          // 64*64 spatial
#define HEADS 8
#define HD 32
#define GROUPS 32
#define EPS_GN 1e-5f

// hd^-0.5 * log2(e): folds softmax scale AND exp->exp2 conversion into k
#define ATT_SCALE (0.17677669529663687f * 1.4426950408889634f)

typedef __attribute__((ext_vector_type(8))) short short8;   // 8 bf16 = 4 VGPR (MFMA A/B frag)
typedef __attribute__((ext_vector_type(4))) float f32x4;    // MFMA C/D frag

static __device__ __forceinline__ unsigned short f2bf(float f) {
    union { float f; unsigned u; } v; v.f = f;
    unsigned r = v.u + 0x7fffu + ((v.u >> 16) & 1u);  // RNE
    return (unsigned short)(r >> 16);
}

// ---------------- K1: GroupNorm stats: one block per (b,group) ----------------
__global__ void k_gnstats(const float* __restrict__ x, float* __restrict__ stats) {
    int bg = blockIdx.x;
    int t = threadIdx.x;
    const float4* b4 = (const float4*)(x + (size_t)bg * (8 * NSP));
    float s = 0.f, sq = 0.f;
    #pragma unroll
    for (int i = 0; i < 32; i++) {
        float4 v = b4[t + i * 256];
        s  += v.x + v.y + v.z + v.w;
        sq += v.x * v.x + v.y * v.y + v.z * v.z + v.w * v.w;
    }
    #pragma unroll
    for (int off = 32; off > 0; off >>= 1) {
        s  += __shfl_down(s, off);
        sq += __shfl_down(sq, off);
    }
    __shared__ float rs[4], rq[4];
    int w = t >> 6;
    if ((t & 63) == 0) { rs[w] = s; rq[w] = sq; }
    __syncthreads();
    if (t == 0) {
        float S = rs[0] + rs[1] + rs[2] + rs[3];
        float Q = rq[0] + rq[1] + rq[2] + rq[3];
        float mu  = S * (1.0f / 32768.0f);
        float var = Q * (1.0f / 32768.0f) - mu * mu;
        stats[bg * 2]     = mu;
        stats[bg * 2 + 1] = rsqrtf(var + EPS_GN);
    }
}

// ------ K2: apply GN, write xn^T (b,p,c) bf16, per-channel partial sums ------
__global__ void k_gnapply(const float* __restrict__ x, const float* __restrict__ gn_w,
                          const float* __restrict__ gn_b, const float* __restrict__ stats,
                          unsigned short* __restrict__ xnt, float* __restrict__ gpart) {
    int p0 = blockIdx.x * 64, c0 = blockIdx.y * 64, b = blockIdx.z;
    int t = threadIdx.x;
    __shared__ float tile[64][65];
    int ci0 = t >> 4, pq = t & 15;
    #pragma unroll
    for (int k = 0; k < 4; k++) {
        int ci = ci0 + k * 16;
        int c = c0 + ci;
        float mu   = stats[(b * GROUPS + (c >> 3)) * 2];
        float rstd = stats[(b * GROUPS + (c >> 3)) * 2 + 1];
        float w  = gn_w[c] * rstd;
        float bb = gn_b[c] - mu * w;
        float4 v = *(const float4*)(x + ((size_t)(b * CH + c)) * NSP + p0 + pq * 4);
        tile[ci][pq * 4 + 0] = v.x * w + bb;
        tile[ci][pq * 4 + 1] = v.y * w + bb;
        tile[ci][pq * 4 + 2] = v.z * w + bb;
        tile[ci][pq * 4 + 3] = v.w * w + bb;
    }
    __syncthreads();
    int pi = t >> 2, cb = (t & 3) * 16;
    unsigned pack[8];
    #pragma unroll
    for (int e = 0; e < 8; e++) {
        float a  = tile[cb + 2 * e][pi];
        float bv = tile[cb + 2 * e + 1][pi];
        pack[e] = (unsigned)f2bf(a) | ((unsigned)f2bf(bv) << 16);
    }
    uint4* dst = (uint4*)(xnt + ((size_t)(b * NSP + p0 + pi)) * CH + c0 + cb);
    dst[0] = make_uint4(pack[0], pack[1], pack[2], pack[3]);
    dst[1] = make_uint4(pack[4], pack[5], pack[6], pack[7]);
    if (t < 64) {
        float s = 0.f;
        #pragma unroll
        for (int j = 0; j < 64; j++) s += tile[t][j];
        gpart[((size_t)(b * CH + c0 + t)) * 64 + blockIdx.x] = s;
    }
}

// -------- K3: gfeat = mean(xn) @ gproj_w^T + gproj_b --------
__global__ void k_gproj(const float* __restrict__ gpart, const float* __restrict__ gproj_w,
                        const float* __restrict__ gproj_b, float* __restrict__ gfeat) {
    int b = blockIdx.x, t = threadIdx.x;
    __shared__ float graw[256];
    const float* p = gpart + ((size_t)(b * CH + t)) * 64;
    float s = 0.f;
    #pragma unroll
    for (int i = 0; i < 64; i++) s += p[i];
    graw[t] = s * (1.0f / 4096.0f);
    __syncthreads();
    float acc = gproj_b[t];
    const float* wr = gproj_w + (size_t)t * CH;
    #pragma unroll 8
    for (int c = 0; c < 256; c++) acc += graw[c] * wr[c];
    gfeat[b * CH + t] = acc;
}

// ---------------- K4: convert qkv_w + proj_w to bf16 ----------------
__global__ void k_convert(const float* __restrict__ qkv_w, const float* __restrict__ proj_w,
                          unsigned short* __restrict__ wbf) {
    int i4 = blockIdx.x * 256 + threadIdx.x;
    const float* src = (i4 < 49152) ? (qkv_w + (size_t)i4 * 4)
                                    : (proj_w + (size_t)(i4 - 49152) * 4);
    float4 v = *(const float4*)src;
    ushort4 o;
    o.x = f2bf(v.x); o.y = f2bf(v.y); o.z = f2bf(v.z); o.w = f2bf(v.w);
    *(ushort4*)(wbf + (size_t)i4 * 4) = o;
}

// ---------------- K5a: QKV GEMM -> bf16 q/k/v in attention layouts ----------------
// A: 768 x 256 bf16 row-major (weights).  B^T: (4096 x 256) per batch (xnt).
// q rows(0..255)  -> qt (b,h,n,hd)
// k rows(256..511)-> kt (b,h,n,hd), value = (acc + bias + 0.1*gfeat) * ATT_SCALE
// v rows(512..767)-> vt (b,h,hd,n)
__global__ void k_gemm_qkv(const unsigned short* __restrict__ Ag,
                           const unsigned short* __restrict__ Btg,
                           const float* __restrict__ bias,
                           const float* __restrict__ gfeat,
                           unsigned short* __restrict__ qt,
                           unsigned short* __restrict__ kt,
                           unsigned short* __restrict__ vt) {
    int n0 = blockIdx.x * 128, m0 = blockIdx.y * 64, b = blockIdx.z;
    int t = threadIdx.x, lane = t & 63, w = t >> 6;
    int wm = w >> 1, wn = w & 1;
    __shared__ short A_lds[64][40];
    __shared__ short B_lds[128][40];
    const unsigned short* Bb = Btg + (size_t)b * NSP * CH;
    f32x4 acc[2][4];
    #pragma unroll
    for (int m = 0; m < 2; m++)
        #pragma unroll
        for (int n = 0; n < 4; n++) acc[m][n] = (f32x4){0.f, 0.f, 0.f, 0.f};
    int arow = t >> 2, akk = (t & 3) * 8;
    for (int k0 = 0; k0 < 256; k0 += 32) {
        __syncthreads();
        *(uint4*)&A_lds[arow][akk] = *(const uint4*)(Ag + (size_t)(m0 + arow) * CH + k0 + akk);
        #pragma unroll
        for (int hh = 0; hh < 2; hh++) {
            int f = t + hh * 256;
            int j = f >> 2, kk = (f & 3) * 8;
            *(uint4*)&B_lds[j][kk] = *(const uint4*)(Bb + (size_t)(n0 + j) * CH + k0 + kk);
        }
        __syncthreads();
        short8 a[2], bf[4];
        #pragma unroll
        for (int m = 0; m < 2; m++)
            a[m] = *(const short8*)&A_lds[wm * 32 + m * 16 + (lane & 15)][(lane >> 4) * 8];
        #pragma unroll
        for (int n = 0; n < 4; n++)
            bf[n] = *(const short8*)&B_lds[wn * 64 + n * 16 + (lane & 15)][(lane >> 4) * 8];
        #pragma unroll
        for (int m = 0; m < 2; m++)
            #pragma unroll
            for (int n = 0; n < 4; n++)
                acc[m][n] = __builtin_amdgcn_mfma_f32_16x16x32_bf16(a[m], bf[n], acc[m][n], 0, 0, 0);
    }
    int rbase = m0 + wm * 32 + ((lane >> 4) << 2);
    int cbase = n0 + wn * 64 + (lane & 15);
    #pragma unroll
    for (int m = 0; m < 2; m++) {
        int row0 = rbase + m * 16;             // 4 consecutive rows, same section+head
        int sec = row0 >> 8;
        int ch  = row0 & 255;
        int h = ch >> 5, d0 = ch & 31;
        #pragma unroll
        for (int n = 0; n < 4; n++) {
            int col = cbase + n * 16;
            if (sec == 0) {
                ushort4 pk;
                pk.x = f2bf(acc[m][n][0] + bias[row0 + 0]);
                pk.y = f2bf(acc[m][n][1] + bias[row0 + 1]);
                pk.z = f2bf(acc[m][n][2] + bias[row0 + 2]);
                pk.w = f2bf(acc[m][n][3] + bias[row0 + 3]);
                *(ushort4*)(qt + ((size_t)((b * 8 + h) * NSP + col)) * HD + d0) = pk;
            } else if (sec == 1) {
                ushort4 pk;
                #pragma unroll
                for (int i = 0; i < 4; i++) {
                    float v = (acc[m][n][i] + bias[row0 + i]
                               + 0.1f * gfeat[b * CH + ch + i]) * ATT_SCALE;
                    ((unsigned short*)&pk)[i] = f2bf(v);
                }
                *(ushort4*)(kt + ((size_t)((b * 8 + h) * NSP + col)) * HD + d0) = pk;
            } else {
                #pragma unroll
                for (int i = 0; i < 4; i++) {
                    float v = acc[m][n][i] + bias[row0 + i];
                    vt[((size_t)((b * 8 + h) * HD + d0 + i)) * NSP + col] = f2bf(v);
                }
            }
        }
    }
}

// ---------------- K5b: proj GEMM (reads att bf16, adds residuals) ----------------
__global__ void k_gemm_proj(const unsigned short* __restrict__ Ag,
                            const unsigned short* __restrict__ Btg,
                            const float* __restrict__ bias,
                            const float* __restrict__ gfeat,
                            const float* __restrict__ xres,
                            float* __restrict__ out) {
    int n0 = blockIdx.x * 128, m0 = blockIdx.y * 64, b = blockIdx.z;
    int t = threadIdx.x, lane = t & 63, w = t >> 6;
    int wm = w >> 1, wn = w & 1;
    __shared__ short A_lds[64][40];
    __shared__ short B_lds[128][40];
    const unsigned short* Bb = Btg + (size_t)b * NSP * CH;
    f32x4 acc[2][4];
    #pragma unroll
    for (int m = 0; m < 2; m++)
        #pragma unroll
        for (int n = 0; n < 4; n++) acc[m][n] = (f32x4){0.f, 0.f, 0.f, 0.f};
    int arow = t >> 2, akk = (t & 3) * 8;
    for (int k0 = 0; k0 < 256; k0 += 32) {
        __syncthreads();
        *(uint4*)&A_lds[arow][akk] = *(const uint4*)(Ag + (size_t)(m0 + arow) * CH + k0 + akk);
        #pragma unroll
        for (int hh = 0; hh < 2; hh++) {
            int f = t + hh * 256;
            int j = f >> 2, kk = (f & 3) * 8;
            *(uint4*)&B_lds[j][kk] = *(const uint4*)(Bb + (size_t)(n0 + j) * CH + k0 + kk);
        }
        __syncthreads();
        short8 a[2], bf[4];
        #pragma unroll
        for (int m = 0; m < 2; m++)
            a[m] = *(const short8*)&A_lds[wm * 32 + m * 16 + (lane & 15)][(lane >> 4) * 8];
        #pragma unroll
        for (int n = 0; n < 4; n++)
            bf[n] = *(const short8*)&B_lds[wn * 64 + n * 16 + (lane & 15)][(lane >> 4) * 8];
        #pragma unroll
        for (int m = 0; m < 2; m++)
            #pragma unroll
            for (int n = 0; n < 4; n++)
                acc[m][n] = __builtin_amdgcn_mfma_f32_16x16x32_bf16(a[m], bf[n], acc[m][n], 0, 0, 0);
    }
    int rbase = m0 + wm * 32 + ((lane >> 4) << 2);
    int cbase = n0 + wn * 64 + (lane & 15);
    #pragma unroll
    for (int m = 0; m < 2; m++) {
        #pragma unroll
        for (int n = 0; n < 4; n++) {
            int col = cbase + n * 16;
            #pragma unroll
            for (int i = 0; i < 4; i++) {
                int row = rbase + m * 16 + i;
                float add = bias[row] + 0.1f * gfeat[b * CH + row]
                          + xres[((size_t)(b * CH + row)) * NSP + col];
                out[((size_t)(b * CH + row)) * NSP + col] = acc[m][n][i] + add;
            }
        }
    }
}

// ------------- K6: bf16 MFMA flash attention -------------
// 4 waves/block, wave owns 16 q-rows. KV tile = 64. hd=32=K of one mfma.
// qt/kt: (b,h,n,32), kt pre-scaled by ATT_SCALE (softmax in exp2 domain).
// vt: (b,h,32,n). Output att: (b,p,c) bf16.
__global__ __launch_bounds__(256)
void k_flash_mfma(const unsigned short* __restrict__ qt,
                  const unsigned short* __restrict__ kt,
                  const unsigned short* __restrict__ vt,
                  unsigned short* __restrict__ att) {
    const int h = blockIdx.y, b = blockIdx.z;
    const int t = threadIdx.x, lane = t & 63, w = t >> 6;
    const int q0 = blockIdx.x * 64 + w * 16;
    const int g = lane >> 4, lo = lane & 15;
    const unsigned short* qp = qt + ((size_t)(b * 8 + h) * NSP) * HD;
    const unsigned short* kp = kt + ((size_t)(b * 8 + h) * NSP) * HD;
    const unsigned short* vp = vt + ((size_t)(b * 8 + h) * HD) * NSP;
    __shared__ __align__(16) unsigned short K_lds[64][40];   // padded: b128 reads 2-way max
    __shared__ __align__(16) unsigned short V_lds[32][72];
    __shared__ __align__(16) unsigned short P_lds[4][16][72]; // per-wave P tile

    short8 qfrag = *(const short8*)(qp + (size_t)(q0 + lo) * HD + g * 8);
    f32x4 oacc[2];
    oacc[0] = (f32x4){0.f, 0.f, 0.f, 0.f};
    oacc[1] = (f32x4){0.f, 0.f, 0.f, 0.f};
    float m[4] = {-1e30f, -1e30f, -1e30f, -1e30f};
    float l[4] = {0.f, 0.f, 0.f, 0.f};

    for (int j0 = 0; j0 < NSP; j0 += 64) {
        __syncthreads();
        *(uint4*)&K_lds[t >> 2][(t & 3) * 8] =
            *(const uint4*)(kp + (size_t)(j0 + (t >> 2)) * HD + (t & 3) * 8);
        *(uint4*)&V_lds[t >> 3][(t & 7) * 8] =
            *(const uint4*)(vp + (size_t)(t >> 3) * NSP + j0 + (t & 7) * 8);
        __syncthreads();

        // S = Q K^T (already scaled+log2e): 4 j-tiles of 16
        f32x4 s[4];
        #pragma unroll
        for (int jt = 0; jt < 4; jt++) {
            short8 kfrag = *(const short8*)&K_lds[jt * 16 + lo][g * 8];
            s[jt] = __builtin_amdgcn_mfma_f32_16x16x32_bf16(
                        qfrag, kfrag, (f32x4){0.f, 0.f, 0.f, 0.f}, 0, 0, 0);
        }
        // online softmax; lane holds rows q = g*4+r, col j = jt*16+lo
        float corr[4];
        #pragma unroll
        for (int r = 0; r < 4; r++) {
            float v0 = fmaxf(fmaxf(s[0][r], s[1][r]), fmaxf(s[2][r], s[3][r]));
            #pragma unroll
            for (int off = 1; off < 16; off <<= 1)
                v0 = fmaxf(v0, __shfl_xor(v0, off, 16));
            float nm = fmaxf(m[r], v0);
            corr[r] = __builtin_amdgcn_exp2f(m[r] - nm);
            m[r] = nm;
        }
        #pragma unroll
        for (int jt = 0; jt < 4; jt++) {
            #pragma unroll
            for (int r = 0; r < 4; r++)
                s[jt][r] = __builtin_amdgcn_exp2f(s[jt][r] - m[r]);
        }
        #pragma unroll
        for (int r = 0; r < 4; r++) {
            float sum = (s[0][r] + s[1][r]) + (s[2][r] + s[3][r]);
            #pragma unroll
            for (int off = 1; off < 16; off <<= 1)
                sum += __shfl_xor(sum, off, 16);
            l[r] = l[r] * corr[r] + sum;
        }
        #pragma unroll
        for (int dt = 0; dt < 2; dt++) {
            oacc[dt][0] *= corr[0]; oacc[dt][1] *= corr[1];
            oacc[dt][2] *= corr[2]; oacc[dt][3] *= corr[3];
        }
        // P -> LDS (bf16), re-fragment as MFMA A operand
        #pragma unroll
        for (int jt = 0; jt < 4; jt++)
            #pragma unroll
            for (int r = 0; r < 4; r++)
                P_lds[w][g * 4 + r][jt * 16 + lo] = f2bf(s[jt][r]);
        // O += P V : 2 j-chunks of 32, 2 d-tiles of 16
        #pragma unroll
        for (int c = 0; c < 2; c++) {
            short8 pa = *(const short8*)&P_lds[w][lo][c * 32 + g * 8];
            #pragma unroll
            for (int dt = 0; dt < 2; dt++) {
                short8 vb = *(const short8*)&V_lds[dt * 16 + lo][c * 32 + g * 8];
                oacc[dt] = __builtin_amdgcn_mfma_f32_16x16x32_bf16(pa, vb, oacc[dt], 0, 0, 0);
            }
        }
    }
    float inv[4];
    #pragma unroll
    for (int r = 0; r < 4; r++) inv[r] = 1.0f / l[r];
    // att (b,p,c): lane holds q=g*4+r, d=dt*16+lo; 16-lane groups write 32B runs
    unsigned short* ap = att + ((size_t)(b * NSP)) * CH + h * HD;
    #pragma unroll
    for (int dt = 0; dt < 2; dt++)
        #pragma unroll
        for (int r = 0; r < 4; r++)
            ap[(size_t)(q0 + g * 4 + r) * CH + dt * 16 + lo] = f2bf(oacc[dt][r] * inv[r]);
}

extern "C" void kernel_launch(void* const* d_in, const int* in_sizes, int n_in,
                              void* d_out, int out_size, void* d_ws, size_t ws_size,
                              hipStream_t stream) {
    const float* x       = (const float*)d_in[0];
    const float* gn_w    = (const float*)d_in[1];
    const float* gn_b    = (const float*)d_in[2];
    const float* qkv_w   = (const float*)d_in[3];
    const float* qkv_b   = (const float*)d_in[4];
    const float* proj_w  = (const float*)d_in[5];
    const float* proj_b  = (const float*)d_in[6];
    const float* gproj_w = (const float*)d_in[7];
    const float* gproj_b = (const float*)d_in[8];
    char* ws = (char*)d_ws;
    // workspace layout (bytes), 256B-aligned; total ~21.6 MB
    float*          stats = (float*)(ws);                      // 512 B
    float*          gpart = (float*)(ws + 1024);               // 128 KB
    float*          gfeat = (float*)(ws + 132096);             // 2 KB
    unsigned short* wbf   = (unsigned short*)(ws + 134144);    // 512 KB bf16 weights
    unsigned short* xnt   = (unsigned short*)(ws + 658432);    // (b,p,c) bf16, 4 MB
    unsigned short* qt    = (unsigned short*)(ws + 4852736);   // (b,h,n,hd) bf16, 4 MB
    unsigned short* kt    = (unsigned short*)(ws + 9047040);   // (b,h,n,hd) bf16, 4 MB
    unsigned short* vt    = (unsigned short*)(ws + 13241344);  // (b,h,hd,n) bf16, 4 MB
    unsigned short* att   = (unsigned short*)(ws + 17435648);  // (b,p,c) bf16, 4 MB
    float* out = (float*)d_out;

    hipLaunchKernelGGL(k_gnstats, dim3(64), dim3(256), 0, stream, x, stats);
    hipLaunchKernelGGL(k_gnapply, dim3(64, 4, 2), dim3(256), 0, stream,
                       x, gn_w, gn_b, stats, xnt, gpart);
    hipLaunchKernelGGL(k_gproj, dim3(2), dim3(256), 0, stream,
                       gpart, gproj_w, gproj_b, gfeat);
    hipLaunchKernelGGL(k_convert, dim3(256), dim3(256), 0, stream, qkv_w, proj_w, wbf);
    hipLaunchKernelGGL(k_gemm_qkv, dim3(32, 12, 2), dim3(256), 0, stream,
                       wbf, xnt, qkv_b, gfeat, qt, kt, vt);
    hipLaunchKernelGGL(k_flash_mfma, dim3(64, 8, 2), dim3(256), 0, stream,
                       qt, kt, vt, att);
    hipLaunchKernelGGL(k_gemm_proj, dim3(32, 4, 2), dim3(256), 0, stream,
                       wbf + 196608, att, proj_b, gfeat, x, out);
}

// Round 3
// 156.195 us; speedup vs baseline: 10.7323x; 1.5504x over previous
//
#include <hip/hip_runtime.h>
#include <hip/hip_bf16.h>
#include <stdint.h>

#define BATCH 2
#define CH 256
#define NSP 4096          // 64*64 spatial
#define HEADS 8
#define HD 32
#define GROUPS 32
#define EPS_GN 1e-5f

// hd^-0.5 * log2(e): folds softmax scale AND exp->exp2 conversion into k
#define ATT_SCALE (0.17677669529663687f * 1.4426950408889634f)

typedef __attribute__((ext_vector_type(8))) short short8;   // 8 bf16 = 4 VGPR (MFMA A/B frag)
typedef __attribute__((ext_vector_type(4))) float f32x4;    // MFMA C/D frag

static __device__ __forceinline__ unsigned short f2bf(float f) {
    union { float f; unsigned u; } v; v.f = f;
    unsigned r = v.u + 0x7fffu + ((v.u >> 16) & 1u);  // RNE
    return (unsigned short)(r >> 16);
}

// ---------------- K1: GroupNorm stats: one block per (b,group) ----------------
__global__ void k_gnstats(const float* __restrict__ x, float* __restrict__ stats) {
    int bg = blockIdx.x;
    int t = threadIdx.x;
    const float4* b4 = (const float4*)(x + (size_t)bg * (8 * NSP));
    float s = 0.f, sq = 0.f;
    #pragma unroll
    for (int i = 0; i < 32; i++) {
        float4 v = b4[t + i * 256];
        s  += v.x + v.y + v.z + v.w;
        sq += v.x * v.x + v.y * v.y + v.z * v.z + v.w * v.w;
    }
    #pragma unroll
    for (int off = 32; off > 0; off >>= 1) {
        s  += __shfl_down(s, off);
        sq += __shfl_down(sq, off);
    }
    __shared__ float rs[4], rq[4];
    int w = t >> 6;
    if ((t & 63) == 0) { rs[w] = s; rq[w] = sq; }
    __syncthreads();
    if (t == 0) {
        float S = rs[0] + rs[1] + rs[2] + rs[3];
        float Q = rq[0] + rq[1] + rq[2] + rq[3];
        float mu  = S * (1.0f / 32768.0f);
        float var = Q * (1.0f / 32768.0f) - mu * mu;
        stats[bg * 2]     = mu;
        stats[bg * 2 + 1] = rsqrtf(var + EPS_GN);
    }
}

// ------ K2: apply GN, write xn^T (b,p,c) bf16, per-channel partial sums ------
__global__ void k_gnapply(const float* __restrict__ x, const float* __restrict__ gn_w,
                          const float* __restrict__ gn_b, const float* __restrict__ stats,
                          unsigned short* __restrict__ xnt, float* __restrict__ gpart) {
    int p0 = blockIdx.x * 64, c0 = blockIdx.y * 64, b = blockIdx.z;
    int t = threadIdx.x;
    __shared__ float tile[64][65];
    int ci0 = t >> 4, pq = t & 15;
    #pragma unroll
    for (int k = 0; k < 4; k++) {
        int ci = ci0 + k * 16;
        int c = c0 + ci;
        float mu   = stats[(b * GROUPS + (c >> 3)) * 2];
        float rstd = stats[(b * GROUPS + (c >> 3)) * 2 + 1];
        float w  = gn_w[c] * rstd;
        float bb = gn_b[c] - mu * w;
        float4 v = *(const float4*)(x + ((size_t)(b * CH + c)) * NSP + p0 + pq * 4);
        tile[ci][pq * 4 + 0] = v.x * w + bb;
        tile[ci][pq * 4 + 1] = v.y * w + bb;
        tile[ci][pq * 4 + 2] = v.z * w + bb;
        tile[ci][pq * 4 + 3] = v.w * w + bb;
    }
    __syncthreads();
    int pi = t >> 2, cb = (t & 3) * 16;
    unsigned pack[8];
    #pragma unroll
    for (int e = 0; e < 8; e++) {
        float a  = tile[cb + 2 * e][pi];
        float bv = tile[cb + 2 * e + 1][pi];
        pack[e] = (unsigned)f2bf(a) | ((unsigned)f2bf(bv) << 16);
    }
    uint4* dst = (uint4*)(xnt + ((size_t)(b * NSP + p0 + pi)) * CH + c0 + cb);
    dst[0] = make_uint4(pack[0], pack[1], pack[2], pack[3]);
    dst[1] = make_uint4(pack[4], pack[5], pack[6], pack[7]);
    if (t < 64) {
        float s = 0.f;
        #pragma unroll
        for (int j = 0; j < 64; j++) s += tile[t][j];
        gpart[((size_t)(b * CH + c0 + t)) * 64 + blockIdx.x] = s;
    }
}

// -------- K3: gfeat = mean(xn) @ gproj_w^T + gproj_b --------
__global__ void k_gproj(const float* __restrict__ gpart, const float* __restrict__ gproj_w,
                        const float* __restrict__ gproj_b, float* __restrict__ gfeat) {
    int b = blockIdx.x, t = threadIdx.x;
    __shared__ float graw[256];
    const float* p = gpart + ((size_t)(b * CH + t)) * 64;
    float s = 0.f;
    #pragma unroll
    for (int i = 0; i < 64; i++) s += p[i];
    graw[t] = s * (1.0f / 4096.0f);
    __syncthreads();
    float acc = gproj_b[t];
    const float* wr = gproj_w + (size_t)t * CH;
    #pragma unroll 8
    for (int c = 0; c < 256; c++) acc += graw[c] * wr[c];
    gfeat[b * CH + t] = acc;
}

// ---------------- K4: convert qkv_w + proj_w to bf16 ----------------
__global__ void k_convert(const float* __restrict__ qkv_w, const float* __restrict__ proj_w,
                          unsigned short* __restrict__ wbf) {
    int i4 = blockIdx.x * 256 + threadIdx.x;
    const float* src = (i4 < 49152) ? (qkv_w + (size_t)i4 * 4)
                                    : (proj_w + (size_t)(i4 - 49152) * 4);
    float4 v = *(const float4*)src;
    ushort4 o;
    o.x = f2bf(v.x); o.y = f2bf(v.y); o.z = f2bf(v.z); o.w = f2bf(v.w);
    *(ushort4*)(wbf + (size_t)i4 * 4) = o;
}

// ---------------- K5a: QKV GEMM -> bf16 q/k/v in attention layouts ----------------
__global__ void k_gemm_qkv(const unsigned short* __restrict__ Ag,
                           const unsigned short* __restrict__ Btg,
                           const float* __restrict__ bias,
                           const float* __restrict__ gfeat,
                           unsigned short* __restrict__ qt,
                           unsigned short* __restrict__ kt,
                           unsigned short* __restrict__ vt) {
    int n0 = blockIdx.x * 128, m0 = blockIdx.y * 64, b = blockIdx.z;
    int t = threadIdx.x, lane = t & 63, w = t >> 6;
    int wm = w >> 1, wn = w & 1;
    __shared__ short A_lds[64][40];
    __shared__ short B_lds[128][40];
    const unsigned short* Bb = Btg + (size_t)b * NSP * CH;
    f32x4 acc[2][4];
    #pragma unroll
    for (int m = 0; m < 2; m++)
        #pragma unroll
        for (int n = 0; n < 4; n++) acc[m][n] = (f32x4){0.f, 0.f, 0.f, 0.f};
    int arow = t >> 2, akk = (t & 3) * 8;
    for (int k0 = 0; k0 < 256; k0 += 32) {
        __syncthreads();
        *(uint4*)&A_lds[arow][akk] = *(const uint4*)(Ag + (size_t)(m0 + arow) * CH + k0 + akk);
        #pragma unroll
        for (int hh = 0; hh < 2; hh++) {
            int f = t + hh * 256;
            int j = f >> 2, kk = (f & 3) * 8;
            *(uint4*)&B_lds[j][kk] = *(const uint4*)(Bb + (size_t)(n0 + j) * CH + k0 + kk);
        }
        __syncthreads();
        short8 a[2], bf[4];
        #pragma unroll
        for (int m = 0; m < 2; m++)
            a[m] = *(const short8*)&A_lds[wm * 32 + m * 16 + (lane & 15)][(lane >> 4) * 8];
        #pragma unroll
        for (int n = 0; n < 4; n++)
            bf[n] = *(const short8*)&B_lds[wn * 64 + n * 16 + (lane & 15)][(lane >> 4) * 8];
        #pragma unroll
        for (int m = 0; m < 2; m++)
            #pragma unroll
            for (int n = 0; n < 4; n++)
                acc[m][n] = __builtin_amdgcn_mfma_f32_16x16x32_bf16(a[m], bf[n], acc[m][n], 0, 0, 0);
    }
    int rbase = m0 + wm * 32 + ((lane >> 4) << 2);
    int cbase = n0 + wn * 64 + (lane & 15);
    #pragma unroll
    for (int m = 0; m < 2; m++) {
        int row0 = rbase + m * 16;
        int sec = row0 >> 8;
        int ch  = row0 & 255;
        int h = ch >> 5, d0 = ch & 31;
        #pragma unroll
        for (int n = 0; n < 4; n++) {
            int col = cbase + n * 16;
            if (sec == 0) {
                ushort4 pk;
                pk.x = f2bf(acc[m][n][0] + bias[row0 + 0]);
                pk.y = f2bf(acc[m][n][1] + bias[row0 + 1]);
                pk.z = f2bf(acc[m][n][2] + bias[row0 + 2]);
                pk.w = f2bf(acc[m][n][3] + bias[row0 + 3]);
                *(ushort4*)(qt + ((size_t)((b * 8 + h) * NSP + col)) * HD + d0) = pk;
            } else if (sec == 1) {
                ushort4 pk;
                #pragma unroll
                for (int i = 0; i < 4; i++) {
                    float v = (acc[m][n][i] + bias[row0 + i]
                               + 0.1f * gfeat[b * CH + ch + i]) * ATT_SCALE;
                    ((unsigned short*)&pk)[i] = f2bf(v);
                }
                *(ushort4*)(kt + ((size_t)((b * 8 + h) * NSP + col)) * HD + d0) = pk;
            } else {
                #pragma unroll
                for (int i = 0; i < 4; i++) {
                    float v = acc[m][n][i] + bias[row0 + i];
                    vt[((size_t)((b * 8 + h) * HD + d0 + i)) * NSP + col] = f2bf(v);
                }
            }
        }
    }
}

// ---------------- K5b: proj GEMM (reads att bf16, adds residuals) ----------------
__global__ void k_gemm_proj(const unsigned short* __restrict__ Ag,
                            const unsigned short* __restrict__ Btg,
                            const float* __restrict__ bias,
                            const float* __restrict__ gfeat,
                            const float* __restrict__ xres,
                            float* __restrict__ out) {
    int n0 = blockIdx.x * 128, m0 = blockIdx.y * 64, b = blockIdx.z;
    int t = threadIdx.x, lane = t & 63, w = t >> 6;
    int wm = w >> 1, wn = w & 1;
    __shared__ short A_lds[64][40];
    __shared__ short B_lds[128][40];
    const unsigned short* Bb = Btg + (size_t)b * NSP * CH;
    f32x4 acc[2][4];
    #pragma unroll
    for (int m = 0; m < 2; m++)
        #pragma unroll
        for (int n = 0; n < 4; n++) acc[m][n] = (f32x4){0.f, 0.f, 0.f, 0.f};
    int arow = t >> 2, akk = (t & 3) * 8;
    for (int k0 = 0; k0 < 256; k0 += 32) {
        __syncthreads();
        *(uint4*)&A_lds[arow][akk] = *(const uint4*)(Ag + (size_t)(m0 + arow) * CH + k0 + akk);
        #pragma unroll
        for (int hh = 0; hh < 2; hh++) {
            int f = t + hh * 256;
            int j = f >> 2, kk = (f & 3) * 8;
            *(uint4*)&B_lds[j][kk] = *(const uint4*)(Bb + (size_t)(n0 + j) * CH + k0 + kk);
        }
        __syncthreads();
        short8 a[2], bf[4];
        #pragma unroll
        for (int m = 0; m < 2; m++)
            a[m] = *(const short8*)&A_lds[wm * 32 + m * 16 + (lane & 15)][(lane >> 4) * 8];
        #pragma unroll
        for (int n = 0; n < 4; n++)
            bf[n] = *(const short8*)&B_lds[wn * 64 + n * 16 + (lane & 15)][(lane >> 4) * 8];
        #pragma unroll
        for (int m = 0; m < 2; m++)
            #pragma unroll
            for (int n = 0; n < 4; n++)
                acc[m][n] = __builtin_amdgcn_mfma_f32_16x16x32_bf16(a[m], bf[n], acc[m][n], 0, 0, 0);
    }
    int rbase = m0 + wm * 32 + ((lane >> 4) << 2);
    int cbase = n0 + wn * 64 + (lane & 15);
    #pragma unroll
    for (int m = 0; m < 2; m++) {
        #pragma unroll
        for (int n = 0; n < 4; n++) {
            int col = cbase + n * 16;
            #pragma unroll
            for (int i = 0; i < 4; i++) {
                int row = rbase + m * 16 + i;
                float add = bias[row] + 0.1f * gfeat[b * CH + row]
                          + xres[((size_t)(b * CH + row)) * NSP + col];
                out[((size_t)(b * CH + row)) * NSP + col] = acc[m][n][i] + add;
            }
        }
    }
}

// ------------- K6: bf16 MFMA flash attention, swapped operands -------------
// S^T = mfma(K, Q): lane holds S[j = jt*16 + g*4 + r][q = lo]  -> per-lane softmax row.
// O^T = mfma(V, P): lane holds O[d = dt*16 + g*4 + r][q = lo].
// qt/kt: (b,h,n,32), kt pre-scaled by ATT_SCALE. vt: (b,h,32,n). att: (b,p,c) bf16.
__global__ __launch_bounds__(256)
void k_flash_mfma(const unsigned short* __restrict__ qt,
                  const unsigned short* __restrict__ kt,
                  const unsigned short* __restrict__ vt,
                  unsigned short* __restrict__ att) {
    const int h = blockIdx.y, b = blockIdx.z;
    const int t = threadIdx.x, lane = t & 63, w = t >> 6;
    const int q0 = blockIdx.x * 64 + w * 16;
    const int g = lane >> 4, lo = lane & 15;
    const unsigned short* qp = qt + ((size_t)(b * 8 + h) * NSP) * HD;
    const unsigned short* kp = kt + ((size_t)(b * 8 + h) * NSP) * HD;
    const unsigned short* vp = vt + ((size_t)(b * 8 + h) * HD) * NSP;
    // strides chosen so each consecutive-8-lane phase tiles the 32 banks
    __shared__ __align__(16) unsigned short K_lds[64][40];
    __shared__ __align__(16) unsigned short V_lds[32][72];
    __shared__ __align__(16) unsigned short P_lds[4][16][80];

    short8 qfrag = *(const short8*)(qp + (size_t)(q0 + lo) * HD + g * 8);
    f32x4 oacc[2];
    oacc[0] = (f32x4){0.f, 0.f, 0.f, 0.f};
    oacc[1] = (f32x4){0.f, 0.f, 0.f, 0.f};
    float m = -1e30f, l = 0.f;

    // T14 async-STAGE: prefetch tile 0 into regs
    const unsigned short* kga = kp + (size_t)(t >> 2) * HD + (t & 3) * 8;
    const unsigned short* vga = vp + (size_t)(t >> 3) * NSP + (t & 7) * 8;
    uint4 kreg = *(const uint4*)(kga);
    uint4 vreg = *(const uint4*)(vga);

    for (int it = 0; it < NSP / 64; ++it) {
        // stage current tile
        *(uint4*)&K_lds[t >> 2][(t & 3) * 8] = kreg;
        *(uint4*)&V_lds[t >> 3][(t & 7) * 8] = vreg;
        __syncthreads();
        if (it + 1 < NSP / 64) {   // issue next-tile loads; land under compute
            kreg = *(const uint4*)(kga + (size_t)(it + 1) * 64 * HD);
            vreg = *(const uint4*)(vga + (it + 1) * 64);
        }

        // S^T = K Q^T : 4 j-tiles of 16
        const f32x4 zero = (f32x4){0.f, 0.f, 0.f, 0.f};
        f32x4 s[4];
        #pragma unroll
        for (int jt = 0; jt < 4; jt++) {
            short8 kfrag = *(const short8*)&K_lds[jt * 16 + lo][g * 8];
            s[jt] = __builtin_amdgcn_mfma_f32_16x16x32_bf16(kfrag, qfrag, zero, 0, 0, 0);
        }
        // per-lane online softmax over the 16 local j-values + cross-g (xor16/32)
        float v01 = fmaxf(fmaxf(s[0][0], s[0][1]), fmaxf(s[0][2], s[0][3]));
        float v23 = fmaxf(fmaxf(s[1][0], s[1][1]), fmaxf(s[1][2], s[1][3]));
        float v45 = fmaxf(fmaxf(s[2][0], s[2][1]), fmaxf(s[2][2], s[2][3]));
        float v67 = fmaxf(fmaxf(s[3][0], s[3][1]), fmaxf(s[3][2], s[3][3]));
        float vmx = fmaxf(fmaxf(v01, v23), fmaxf(v45, v67));
        vmx = fmaxf(vmx, __shfl_xor(vmx, 16));
        vmx = fmaxf(vmx, __shfl_xor(vmx, 32));
        float nm = fmaxf(m, vmx);
        float corr = __builtin_amdgcn_exp2f(m - nm);
        m = nm;
        #pragma unroll
        for (int jt = 0; jt < 4; jt++) {
            #pragma unroll
            for (int r = 0; r < 4; r++)
                s[jt][r] = __builtin_amdgcn_exp2f(s[jt][r] - nm);
        }
        float sm = ((s[0][0] + s[0][1]) + (s[0][2] + s[0][3]))
                 + ((s[1][0] + s[1][1]) + (s[1][2] + s[1][3]))
                 + ((s[2][0] + s[2][1]) + (s[2][2] + s[2][3]))
                 + ((s[3][0] + s[3][1]) + (s[3][2] + s[3][3]));
        sm += __shfl_xor(sm, 16);
        sm += __shfl_xor(sm, 32);
        l = l * corr + sm;
        #pragma unroll
        for (int dt = 0; dt < 2; dt++) {
            oacc[dt][0] *= corr; oacc[dt][1] *= corr;
            oacc[dt][2] *= corr; oacc[dt][3] *= corr;
        }
        // P -> LDS: lane owns P[j=jt*16+g*4+r][q=lo]; pack 4 bf16, one b64 per jt
        #pragma unroll
        for (int jt = 0; jt < 4; jt++) {
            __hip_bfloat162 p0 = __float22bfloat162_rn(make_float2(s[jt][0], s[jt][1]));
            __hip_bfloat162 p1 = __float22bfloat162_rn(make_float2(s[jt][2], s[jt][3]));
            uint2 pw;
            pw.x = *(unsigned*)&p0;
            pw.y = *(unsigned*)&p1;
            *(uint2*)&P_lds[w][lo][jt * 16 + g * 4] = pw;
        }
        // O^T += V P : B-frag = P[j = c*32+g*8 .. +8][q=lo] (contiguous, 16B aligned)
        #pragma unroll
        for (int c = 0; c < 2; c++) {
            short8 pa = *(const short8*)&P_lds[w][lo][c * 32 + g * 8];
            #pragma unroll
            for (int dt = 0; dt < 2; dt++) {
                short8 vb = *(const short8*)&V_lds[dt * 16 + lo][c * 32 + g * 8];
                oacc[dt] = __builtin_amdgcn_mfma_f32_16x16x32_bf16(vb, pa, oacc[dt], 0, 0, 0);
            }
        }
        __syncthreads();   // protect K_lds/V_lds before next stage
    }
    float inv = 1.0f / l;
    // lane holds q=lo, d = dt*16 + g*4 + r  -> 2x ushort4 stores
    unsigned short* ap = att + ((size_t)(b * NSP + q0 + lo)) * CH + h * HD;
    #pragma unroll
    for (int dt = 0; dt < 2; dt++) {
        ushort4 pk;
        pk.x = f2bf(oacc[dt][0] * inv);
        pk.y = f2bf(oacc[dt][1] * inv);
        pk.z = f2bf(oacc[dt][2] * inv);
        pk.w = f2bf(oacc[dt][3] * inv);
        *(ushort4*)(ap + dt * 16 + g * 4) = pk;
    }
}

extern "C" void kernel_launch(void* const* d_in, const int* in_sizes, int n_in,
                              void* d_out, int out_size, void* d_ws, size_t ws_size,
                              hipStream_t stream) {
    const float* x       = (const float*)d_in[0];
    const float* gn_w    = (const float*)d_in[1];
    const float* gn_b    = (const float*)d_in[2];
    const float* qkv_w   = (const float*)d_in[3];
    const float* qkv_b   = (const float*)d_in[4];
    const float* proj_w  = (const float*)d_in[5];
    const float* proj_b  = (const float*)d_in[6];
    const float* gproj_w = (const float*)d_in[7];
    const float* gproj_b = (const float*)d_in[8];
    char* ws = (char*)d_ws;
    float*          stats = (float*)(ws);                      // 512 B
    float*          gpart = (float*)(ws + 1024);               // 128 KB
    float*          gfeat = (float*)(ws + 132096);             // 2 KB
    unsigned short* wbf   = (unsigned short*)(ws + 134144);    // 512 KB bf16 weights
    unsigned short* xnt   = (unsigned short*)(ws + 658432);    // (b,p,c) bf16, 4 MB
    unsigned short* qt    = (unsigned short*)(ws + 4852736);   // (b,h,n,hd) bf16, 4 MB
    unsigned short* kt    = (unsigned short*)(ws + 9047040);   // (b,h,n,hd) bf16, 4 MB
    unsigned short* vt    = (unsigned short*)(ws + 13241344);  // (b,h,hd,n) bf16, 4 MB
    unsigned short* att   = (unsigned short*)(ws + 17435648);  // (b,p,c) bf16, 4 MB
    float* out = (float*)d_out;

    hipLaunchKernelGGL(k_gnstats, dim3(64), dim3(256), 0, stream, x, stats);
    hipLaunchKernelGGL(k_gnapply, dim3(64, 4, 2), dim3(256), 0, stream,
                       x, gn_w, gn_b, stats, xnt, gpart);
    hipLaunchKernelGGL(k_gproj, dim3(2), dim3(256), 0, stream,
                       gpart, gproj_w, gproj_b, gfeat);
    hipLaunchKernelGGL(k_convert, dim3(256), dim3(256), 0, stream, qkv_w, proj_w, wbf);
    hipLaunchKernelGGL(k_gemm_qkv, dim3(32, 12, 2), dim3(256), 0, stream,
                       wbf, xnt, qkv_b, gfeat, qt, kt, vt);
    hipLaunchKernelGGL(k_flash_mfma, dim3(64, 8, 2), dim3(256), 0, stream,
                       qt, kt, vt, att);
    hipLaunchKernelGGL(k_gemm_proj, dim3(32, 4, 2), dim3(256), 0, stream,
                       wbf + 196608, att, proj_b, gfeat, x, out);
}

// Round 4
// 141.023 us; speedup vs baseline: 11.8870x; 1.1076x over previous
//
#include <hip/hip_runtime.h>
#include <hip/hip_bf16.h>
#include <stdint.h>

#define BATCH 2
#define CH 256
#define NSP 4096          // 64*64 spatial
#define HEADS 8
#define HD 32
#define GROUPS 32
#define EPS_GN 1e-5f
#define NSPLIT 2          // flash KV-sequence splits

// hd^-0.5 * log2(e): folds softmax scale AND exp->exp2 conversion into k
#define ATT_SCALE (0.17677669529663687f * 1.4426950408889634f)

typedef __attribute__((ext_vector_type(8))) short short8;   // 8 bf16 = 4 VGPR (MFMA A/B frag)
typedef __attribute__((ext_vector_type(4))) float f32x4;    // MFMA C/D frag

static __device__ __forceinline__ unsigned short f2bf(float f) {
    union { float f; unsigned u; } v; v.f = f;
    unsigned r = v.u + 0x7fffu + ((v.u >> 16) & 1u);  // RNE
    return (unsigned short)(r >> 16);
}

// ---------------- K1: GroupNorm stats: one block per (b,group) ----------------
__global__ void k_gnstats(const float* __restrict__ x, float* __restrict__ stats) {
    int bg = blockIdx.x;
    int t = threadIdx.x;
    const float4* b4 = (const float4*)(x + (size_t)bg * (8 * NSP));
    float s = 0.f, sq = 0.f;
    #pragma unroll
    for (int i = 0; i < 32; i++) {
        float4 v = b4[t + i * 256];
        s  += v.x + v.y + v.z + v.w;
        sq += v.x * v.x + v.y * v.y + v.z * v.z + v.w * v.w;
    }
    #pragma unroll
    for (int off = 32; off > 0; off >>= 1) {
        s  += __shfl_down(s, off);
        sq += __shfl_down(sq, off);
    }
    __shared__ float rs[4], rq[4];
    int w = t >> 6;
    if ((t & 63) == 0) { rs[w] = s; rq[w] = sq; }
    __syncthreads();
    if (t == 0) {
        float S = rs[0] + rs[1] + rs[2] + rs[3];
        float Q = rq[0] + rq[1] + rq[2] + rq[3];
        float mu  = S * (1.0f / 32768.0f);
        float var = Q * (1.0f / 32768.0f) - mu * mu;
        stats[bg * 2]     = mu;
        stats[bg * 2 + 1] = rsqrtf(var + EPS_GN);
    }
}

// ------ K2: apply GN, write xn^T (b,p,c) bf16, per-channel partial sums ------
__global__ void k_gnapply(const float* __restrict__ x, const float* __restrict__ gn_w,
                          const float* __restrict__ gn_b, const float* __restrict__ stats,
                          unsigned short* __restrict__ xnt, float* __restrict__ gpart) {
    int p0 = blockIdx.x * 64, c0 = blockIdx.y * 64, b = blockIdx.z;
    int t = threadIdx.x;
    __shared__ float tile[64][65];
    int ci0 = t >> 4, pq = t & 15;
    #pragma unroll
    for (int k = 0; k < 4; k++) {
        int ci = ci0 + k * 16;
        int c = c0 + ci;
        float mu   = stats[(b * GROUPS + (c >> 3)) * 2];
        float rstd = stats[(b * GROUPS + (c >> 3)) * 2 + 1];
        float w  = gn_w[c] * rstd;
        float bb = gn_b[c] - mu * w;
        float4 v = *(const float4*)(x + ((size_t)(b * CH + c)) * NSP + p0 + pq * 4);
        tile[ci][pq * 4 + 0] = v.x * w + bb;
        tile[ci][pq * 4 + 1] = v.y * w + bb;
        tile[ci][pq * 4 + 2] = v.z * w + bb;
        tile[ci][pq * 4 + 3] = v.w * w + bb;
    }
    __syncthreads();
    int pi = t >> 2, cb = (t & 3) * 16;
    unsigned pack[8];
    #pragma unroll
    for (int e = 0; e < 8; e++) {
        float a  = tile[cb + 2 * e][pi];
        float bv = tile[cb + 2 * e + 1][pi];
        pack[e] = (unsigned)f2bf(a) | ((unsigned)f2bf(bv) << 16);
    }
    uint4* dst = (uint4*)(xnt + ((size_t)(b * NSP + p0 + pi)) * CH + c0 + cb);
    dst[0] = make_uint4(pack[0], pack[1], pack[2], pack[3]);
    dst[1] = make_uint4(pack[4], pack[5], pack[6], pack[7]);
    if (t < 64) {
        float s = 0.f;
        #pragma unroll
        for (int j = 0; j < 64; j++) s += tile[t][j];
        gpart[((size_t)(b * CH + c0 + t)) * 64 + blockIdx.x] = s;
    }
}

// -------- K3: gfeat = mean(xn) @ gproj_w^T + gproj_b --------
__global__ void k_gproj(const float* __restrict__ gpart, const float* __restrict__ gproj_w,
                        const float* __restrict__ gproj_b, float* __restrict__ gfeat) {
    int b = blockIdx.x, t = threadIdx.x;
    __shared__ float graw[256];
    const float* p = gpart + ((size_t)(b * CH + t)) * 64;
    float s = 0.f;
    #pragma unroll
    for (int i = 0; i < 64; i++) s += p[i];
    graw[t] = s * (1.0f / 4096.0f);
    __syncthreads();
    float acc = gproj_b[t];
    const float* wr = gproj_w + (size_t)t * CH;
    #pragma unroll 8
    for (int c = 0; c < 256; c++) acc += graw[c] * wr[c];
    gfeat[b * CH + t] = acc;
}

// ---------------- K4: convert qkv_w + proj_w to bf16 ----------------
__global__ void k_convert(const float* __restrict__ qkv_w, const float* __restrict__ proj_w,
                          unsigned short* __restrict__ wbf) {
    int i4 = blockIdx.x * 256 + threadIdx.x;
    const float* src = (i4 < 49152) ? (qkv_w + (size_t)i4 * 4)
                                    : (proj_w + (size_t)(i4 - 49152) * 4);
    float4 v = *(const float4*)src;
    ushort4 o;
    o.x = f2bf(v.x); o.y = f2bf(v.y); o.z = f2bf(v.z); o.w = f2bf(v.w);
    *(ushort4*)(wbf + (size_t)i4 * 4) = o;
}

// ---------------- K5a: QKV GEMM -> bf16 q/k/v in attention layouts ----------------
__global__ void k_gemm_qkv(const unsigned short* __restrict__ Ag,
                           const unsigned short* __restrict__ Btg,
                           const float* __restrict__ bias,
                           const float* __restrict__ gfeat,
                           unsigned short* __restrict__ qt,
                           unsigned short* __restrict__ kt,
                           unsigned short* __restrict__ vt) {
    int n0 = blockIdx.x * 128, m0 = blockIdx.y * 64, b = blockIdx.z;
    int t = threadIdx.x, lane = t & 63, w = t >> 6;
    int wm = w >> 1, wn = w & 1;
    __shared__ short A_lds[64][40];
    __shared__ short B_lds[128][40];
    const unsigned short* Bb = Btg + (size_t)b * NSP * CH;
    f32x4 acc[2][4];
    #pragma unroll
    for (int m = 0; m < 2; m++)
        #pragma unroll
        for (int n = 0; n < 4; n++) acc[m][n] = (f32x4){0.f, 0.f, 0.f, 0.f};
    int arow = t >> 2, akk = (t & 3) * 8;
    for (int k0 = 0; k0 < 256; k0 += 32) {
        __syncthreads();
        *(uint4*)&A_lds[arow][akk] = *(const uint4*)(Ag + (size_t)(m0 + arow) * CH + k0 + akk);
        #pragma unroll
        for (int hh = 0; hh < 2; hh++) {
            int f = t + hh * 256;
            int j = f >> 2, kk = (f & 3) * 8;
            *(uint4*)&B_lds[j][kk] = *(const uint4*)(Bb + (size_t)(n0 + j) * CH + k0 + kk);
        }
        __syncthreads();
        short8 a[2], bf[4];
        #pragma unroll
        for (int m = 0; m < 2; m++)
            a[m] = *(const short8*)&A_lds[wm * 32 + m * 16 + (lane & 15)][(lane >> 4) * 8];
        #pragma unroll
        for (int n = 0; n < 4; n++)
            bf[n] = *(const short8*)&B_lds[wn * 64 + n * 16 + (lane & 15)][(lane >> 4) * 8];
        #pragma unroll
        for (int m = 0; m < 2; m++)
            #pragma unroll
            for (int n = 0; n < 4; n++)
                acc[m][n] = __builtin_amdgcn_mfma_f32_16x16x32_bf16(a[m], bf[n], acc[m][n], 0, 0, 0);
    }
    int rbase = m0 + wm * 32 + ((lane >> 4) << 2);
    int cbase = n0 + wn * 64 + (lane & 15);
    #pragma unroll
    for (int m = 0; m < 2; m++) {
        int row0 = rbase + m * 16;
        int sec = row0 >> 8;
        int ch  = row0 & 255;
        int h = ch >> 5, d0 = ch & 31;
        #pragma unroll
        for (int n = 0; n < 4; n++) {
            int col = cbase + n * 16;
            if (sec == 0) {
                ushort4 pk;
                pk.x = f2bf(acc[m][n][0] + bias[row0 + 0]);
                pk.y = f2bf(acc[m][n][1] + bias[row0 + 1]);
                pk.z = f2bf(acc[m][n][2] + bias[row0 + 2]);
                pk.w = f2bf(acc[m][n][3] + bias[row0 + 3]);
                *(ushort4*)(qt + ((size_t)((b * 8 + h) * NSP + col)) * HD + d0) = pk;
            } else if (sec == 1) {
                ushort4 pk;
                #pragma unroll
                for (int i = 0; i < 4; i++) {
                    float v = (acc[m][n][i] + bias[row0 + i]
                               + 0.1f * gfeat[b * CH + ch + i]) * ATT_SCALE;
                    ((unsigned short*)&pk)[i] = f2bf(v);
                }
                *(ushort4*)(kt + ((size_t)((b * 8 + h) * NSP + col)) * HD + d0) = pk;
            } else {
                #pragma unroll
                for (int i = 0; i < 4; i++) {
                    float v = acc[m][n][i] + bias[row0 + i];
                    vt[((size_t)((b * 8 + h) * HD + d0 + i)) * NSP + col] = f2bf(v);
                }
            }
        }
    }
}

// ---------------- K5b: proj GEMM (reads att bf16, adds residuals) ----------------
__global__ void k_gemm_proj(const unsigned short* __restrict__ Ag,
                            const unsigned short* __restrict__ Btg,
                            const float* __restrict__ bias,
                            const float* __restrict__ gfeat,
                            const float* __restrict__ xres,
                            float* __restrict__ out) {
    int n0 = blockIdx.x * 128, m0 = blockIdx.y * 64, b = blockIdx.z;
    int t = threadIdx.x, lane = t & 63, w = t >> 6;
    int wm = w >> 1, wn = w & 1;
    __shared__ short A_lds[64][40];
    __shared__ short B_lds[128][40];
    const unsigned short* Bb = Btg + (size_t)b * NSP * CH;
    f32x4 acc[2][4];
    #pragma unroll
    for (int m = 0; m < 2; m++)
        #pragma unroll
        for (int n = 0; n < 4; n++) acc[m][n] = (f32x4){0.f, 0.f, 0.f, 0.f};
    int arow = t >> 2, akk = (t & 3) * 8;
    for (int k0 = 0; k0 < 256; k0 += 32) {
        __syncthreads();
        *(uint4*)&A_lds[arow][akk] = *(const uint4*)(Ag + (size_t)(m0 + arow) * CH + k0 + akk);
        #pragma unroll
        for (int hh = 0; hh < 2; hh++) {
            int f = t + hh * 256;
            int j = f >> 2, kk = (f & 3) * 8;
            *(uint4*)&B_lds[j][kk] = *(const uint4*)(Bb + (size_t)(n0 + j) * CH + k0 + kk);
        }
        __syncthreads();
        short8 a[2], bf[4];
        #pragma unroll
        for (int m = 0; m < 2; m++)
            a[m] = *(const short8*)&A_lds[wm * 32 + m * 16 + (lane & 15)][(lane >> 4) * 8];
        #pragma unroll
        for (int n = 0; n < 4; n++)
            bf[n] = *(const short8*)&B_lds[wn * 64 + n * 16 + (lane & 15)][(lane >> 4) * 8];
        #pragma unroll
        for (int m = 0; m < 2; m++)
            #pragma unroll
            for (int n = 0; n < 4; n++)
                acc[m][n] = __builtin_amdgcn_mfma_f32_16x16x32_bf16(a[m], bf[n], acc[m][n], 0, 0, 0);
    }
    int rbase = m0 + wm * 32 + ((lane >> 4) << 2);
    int cbase = n0 + wn * 64 + (lane & 15);
    #pragma unroll
    for (int m = 0; m < 2; m++) {
        #pragma unroll
        for (int n = 0; n < 4; n++) {
            int col = cbase + n * 16;
            #pragma unroll
            for (int i = 0; i < 4; i++) {
                int row = rbase + m * 16 + i;
                float add = bias[row] + 0.1f * gfeat[b * CH + row]
                          + xres[((size_t)(b * CH + row)) * NSP + col];
                out[((size_t)(b * CH + row)) * NSP + col] = acc[m][n][i] + add;
            }
        }
    }
}

// ------------- K6: bf16 MFMA flash attention, swapped operands, split-KV -------------
// blockIdx.x: qtile (0..63) + 64*split.  Each block: 16q x 4 waves over a 2048-j half.
// S^T = mfma(K, Q): lane holds S[j][q=lo]. O^T = mfma(V, P): lane holds O[d][q=lo].
// Outputs fp32 partials: opart[s][b][h][q][d] (unnormalized), lmpart[s][b][h][q] = {m,l}.
__global__ __launch_bounds__(256)
void k_flash_split(const unsigned short* __restrict__ qt,
                   const unsigned short* __restrict__ kt,
                   const unsigned short* __restrict__ vt,
                   float* __restrict__ opart, float* __restrict__ lmpart) {
    const int h = blockIdx.y, b = blockIdx.z;
    const int s = blockIdx.x >> 6;
    const int q0 = (blockIdx.x & 63) * 64 + (threadIdx.x >> 6) * 16;
    const int t = threadIdx.x, lane = t & 63, w = t >> 6;
    const int g = lane >> 4, lo = lane & 15;
    const int j0base = s * (NSP / NSPLIT);
    const unsigned short* qp = qt + ((size_t)(b * 8 + h) * NSP) * HD;
    const unsigned short* kp = kt + ((size_t)(b * 8 + h) * NSP) * HD;
    const unsigned short* vp = vt + ((size_t)(b * 8 + h) * HD) * NSP;
    // strides: K 80B (20 banks), V/P 144B (36 banks) -> conflict-free b128 phases
    __shared__ __align__(16) unsigned short K_lds[64][40];
    __shared__ __align__(16) unsigned short V_lds[32][72];
    __shared__ __align__(16) unsigned short P_lds[4][16][72];

    short8 qfrag = *(const short8*)(qp + (size_t)(q0 + lo) * HD + g * 8);
    f32x4 oacc[2];
    oacc[0] = (f32x4){0.f, 0.f, 0.f, 0.f};
    oacc[1] = (f32x4){0.f, 0.f, 0.f, 0.f};
    float m = -1e30f, l = 0.f;

    // T14 async-STAGE: prefetch tile 0 into regs
    const unsigned short* kga = kp + (size_t)(j0base + (t >> 2)) * HD + (t & 3) * 8;
    const unsigned short* vga = vp + (size_t)(t >> 3) * NSP + j0base + (t & 7) * 8;
    uint4 kreg = *(const uint4*)(kga);
    uint4 vreg = *(const uint4*)(vga);

    const int NT = NSP / NSPLIT / 64;
    for (int it = 0; it < NT; ++it) {
        *(uint4*)&K_lds[t >> 2][(t & 3) * 8] = kreg;
        *(uint4*)&V_lds[t >> 3][(t & 7) * 8] = vreg;
        __syncthreads();
        if (it + 1 < NT) {   // issue next-tile loads; land under compute
            kreg = *(const uint4*)(kga + (size_t)(it + 1) * 64 * HD);
            vreg = *(const uint4*)(vga + (it + 1) * 64);
        }

        // S^T = K Q^T : 4 j-tiles of 16
        const f32x4 zero = (f32x4){0.f, 0.f, 0.f, 0.f};
        f32x4 sv[4];
        __builtin_amdgcn_s_setprio(1);
        #pragma unroll
        for (int jt = 0; jt < 4; jt++) {
            short8 kfrag = *(const short8*)&K_lds[jt * 16 + lo][g * 8];
            sv[jt] = __builtin_amdgcn_mfma_f32_16x16x32_bf16(kfrag, qfrag, zero, 0, 0, 0);
        }
        __builtin_amdgcn_s_setprio(0);
        // per-lane tile max (max3-friendly triples), then cross-g xor16/32
        float t0 = fmaxf(fmaxf(sv[0][0], sv[0][1]), sv[0][2]);
        float t1 = fmaxf(fmaxf(sv[0][3], sv[1][0]), sv[1][1]);
        float t2 = fmaxf(fmaxf(sv[1][2], sv[1][3]), sv[2][0]);
        float t3 = fmaxf(fmaxf(sv[2][1], sv[2][2]), sv[2][3]);
        float t4 = fmaxf(fmaxf(sv[3][0], sv[3][1]), sv[3][2]);
        float vmx = fmaxf(fmaxf(fmaxf(t0, t1), t2), fmaxf(fmaxf(t3, t4), sv[3][3]));
        vmx = fmaxf(vmx, __shfl_xor(vmx, 16));
        vmx = fmaxf(vmx, __shfl_xor(vmx, 32));
        // T13 defer-max: skip rescale when no q-row in the wave grew its max
        if (__any(vmx > m)) {
            float nm = fmaxf(m, vmx);
            float corr = __builtin_amdgcn_exp2f(m - nm);
            m = nm;
            l *= corr;
            #pragma unroll
            for (int dt = 0; dt < 2; dt++) {
                oacc[dt][0] *= corr; oacc[dt][1] *= corr;
                oacc[dt][2] *= corr; oacc[dt][3] *= corr;
            }
        }
        #pragma unroll
        for (int jt = 0; jt < 4; jt++) {
            #pragma unroll
            for (int r = 0; r < 4; r++)
                sv[jt][r] = __builtin_amdgcn_exp2f(sv[jt][r] - m);
        }
        float sm = ((sv[0][0] + sv[0][1]) + (sv[0][2] + sv[0][3]))
                 + ((sv[1][0] + sv[1][1]) + (sv[1][2] + sv[1][3]))
                 + ((sv[2][0] + sv[2][1]) + (sv[2][2] + sv[2][3]))
                 + ((sv[3][0] + sv[3][1]) + (sv[3][2] + sv[3][3]));
        sm += __shfl_xor(sm, 16);
        sm += __shfl_xor(sm, 32);
        l += sm;
        // P -> LDS: lane owns P[j=jt*16+g*4+r][q=lo]; 4x b64 (2-way max = free)
        #pragma unroll
        for (int jt = 0; jt < 4; jt++) {
            __hip_bfloat162 p0 = __float22bfloat162_rn(make_float2(sv[jt][0], sv[jt][1]));
            __hip_bfloat162 p1 = __float22bfloat162_rn(make_float2(sv[jt][2], sv[jt][3]));
            uint2 pw;
            pw.x = *(unsigned*)&p0;
            pw.y = *(unsigned*)&p1;
            *(uint2*)&P_lds[w][lo][jt * 16 + g * 4] = pw;
        }
        // O^T += V P
        __builtin_amdgcn_s_setprio(1);
        #pragma unroll
        for (int c = 0; c < 2; c++) {
            short8 pa = *(const short8*)&P_lds[w][lo][c * 32 + g * 8];
            #pragma unroll
            for (int dt = 0; dt < 2; dt++) {
                short8 vb = *(const short8*)&V_lds[dt * 16 + lo][c * 32 + g * 8];
                oacc[dt] = __builtin_amdgcn_mfma_f32_16x16x32_bf16(vb, pa, oacc[dt], 0, 0, 0);
            }
        }
        __builtin_amdgcn_s_setprio(0);
        __syncthreads();   // protect K_lds/V_lds before next stage
    }
    // fp32 partials; wave covers full 128B rows (coalesced at line level)
    float* op = opart + ((((size_t)s * BATCH + b) * HEADS + h) * NSP + q0 + lo) * HD;
    #pragma unroll
    for (int dt = 0; dt < 2; dt++)
        *(float4*)(op + dt * 16 + g * 4) =
            make_float4(oacc[dt][0], oacc[dt][1], oacc[dt][2], oacc[dt][3]);
    if (g == 0) {
        float2 lm = make_float2(m, l);
        *(float2*)(lmpart + ((((size_t)s * BATCH + b) * HEADS + h) * NSP + q0 + lo) * 2) = lm;
    }
}

// ------------- K7: combine split partials -> att bf16 (b,p,c) -------------
__global__ __launch_bounds__(256)
void k_combine(const float* __restrict__ opart, const float* __restrict__ lmpart,
               unsigned short* __restrict__ att) {
    const int bh = blockIdx.y;            // b*8+h
    const int b = bh >> 3, h = bh & 7;
    const int t = threadIdx.x;
    const int q = blockIdx.x * 32 + (t >> 3);
    const int dq = (t & 7) * 4;
    const size_t sO = (size_t)BATCH * HEADS * NSP * HD;   // opart split stride
    const size_t sL = (size_t)BATCH * HEADS * NSP * 2;    // lmpart split stride
    const size_t rowq = (size_t)bh * NSP + q;
    float2 lm1 = *(const float2*)(lmpart + rowq * 2);
    float2 lm2 = *(const float2*)(lmpart + sL + rowq * 2);
    float M = fmaxf(lm1.x, lm2.x);
    float c1 = __builtin_amdgcn_exp2f(lm1.x - M);
    float c2 = __builtin_amdgcn_exp2f(lm2.x - M);
    float inv = 1.0f / (lm1.y * c1 + lm2.y * c2);
    c1 *= inv; c2 *= inv;
    float4 o1 = *(const float4*)(opart + rowq * HD + dq);
    float4 o2 = *(const float4*)(opart + sO + rowq * HD + dq);
    ushort4 pk;
    pk.x = f2bf(o1.x * c1 + o2.x * c2);
    pk.y = f2bf(o1.y * c1 + o2.y * c2);
    pk.z = f2bf(o1.z * c1 + o2.z * c2);
    pk.w = f2bf(o1.w * c1 + o2.w * c2);
    *(ushort4*)(att + ((size_t)(b * NSP + q)) * CH + h * HD + dq) = pk;
}

extern "C" void kernel_launch(void* const* d_in, const int* in_sizes, int n_in,
                              void* d_out, int out_size, void* d_ws, size_t ws_size,
                              hipStream_t stream) {
    const float* x       = (const float*)d_in[0];
    const float* gn_w    = (const float*)d_in[1];
    const float* gn_b    = (const float*)d_in[2];
    const float* qkv_w   = (const float*)d_in[3];
    const float* qkv_b   = (const float*)d_in[4];
    const float* proj_w  = (const float*)d_in[5];
    const float* proj_b  = (const float*)d_in[6];
    const float* gproj_w = (const float*)d_in[7];
    const float* gproj_b = (const float*)d_in[8];
    char* ws = (char*)d_ws;
    float*          stats  = (float*)(ws);                      // 512 B
    float*          gpart  = (float*)(ws + 1024);               // 128 KB
    float*          gfeat  = (float*)(ws + 132096);             // 2 KB
    unsigned short* wbf    = (unsigned short*)(ws + 134144);    // 512 KB bf16 weights
    unsigned short* xnt    = (unsigned short*)(ws + 658432);    // (b,p,c) bf16, 4 MB
    unsigned short* qt     = (unsigned short*)(ws + 4852736);   // (b,h,n,hd) bf16, 4 MB
    unsigned short* kt     = (unsigned short*)(ws + 9047040);   // (b,h,n,hd) bf16, 4 MB
    unsigned short* vt     = (unsigned short*)(ws + 13241344);  // (b,h,hd,n) bf16, 4 MB
    unsigned short* att    = (unsigned short*)(ws + 17435648);  // (b,p,c) bf16, 4 MB
    float*          opart  = (float*)(ws + 21629952);           // 2 splits fp32 O, 16 MB
    float*          lmpart = (float*)(ws + 38407168);           // {m,l} per q, 1 MB
    float* out = (float*)d_out;

    hipLaunchKernelGGL(k_gnstats, dim3(64), dim3(256), 0, stream, x, stats);
    hipLaunchKernelGGL(k_gnapply, dim3(64, 4, 2), dim3(256), 0, stream,
                       x, gn_w, gn_b, stats, xnt, gpart);
    hipLaunchKernelGGL(k_gproj, dim3(2), dim3(256), 0, stream,
                       gpart, gproj_w, gproj_b, gfeat);
    hipLaunchKernelGGL(k_convert, dim3(256), dim3(256), 0, stream, qkv_w, proj_w, wbf);
    hipLaunchKernelGGL(k_gemm_qkv, dim3(32, 12, 2), dim3(256), 0, stream,
                       wbf, xnt, qkv_b, gfeat, qt, kt, vt);
    hipLaunchKernelGGL(k_flash_split, dim3(64 * NSPLIT, 8, 2), dim3(256), 0, stream,
                       qt, kt, vt, opart, lmpart);
    hipLaunchKernelGGL(k_combine, dim3(128, 16), dim3(256), 0, stream,
                       opart, lmpart, att);
    hipLaunchKernelGGL(k_gemm_proj, dim3(32, 4, 2), dim3(256), 0, stream,
                       wbf + 196608, att, proj_b, gfeat, x, out);
}

// Round 5
// 132.828 us; speedup vs baseline: 12.6204x; 1.0617x over previous
//
#include <hip/hip_runtime.h>
#include <hip/hip_bf16.h>
#include <stdint.h>

#define BATCH 2
#define CH 256
#define NSP 4096          // 64*64 spatial
#define HEADS 8
#define HD 32
#define GROUPS 32
#define EPS_GN 1e-5f
#define NSPLIT 4          // flash KV-sequence splits

// hd^-0.5 * log2(e): folds softmax scale AND exp->exp2 conversion into k
#define ATT_SCALE (0.17677669529663687f * 1.4426950408889634f)

typedef __attribute__((ext_vector_type(8))) short short8;    // 8 bf16 (MFMA A/B frag)
typedef __attribute__((ext_vector_type(4))) float f32x4;     // 16x16 C/D frag
typedef __attribute__((ext_vector_type(16))) float f32x16;   // 32x32 C/D frag

#define ZERO16 ((f32x16){0.f,0.f,0.f,0.f,0.f,0.f,0.f,0.f,0.f,0.f,0.f,0.f,0.f,0.f,0.f,0.f})

static __device__ __forceinline__ unsigned short f2bf(float f) {
    union { float f; unsigned u; } v; v.f = f;
    unsigned r = v.u + 0x7fffu + ((v.u >> 16) & 1u);  // RNE
    return (unsigned short)(r >> 16);
}
static __device__ __forceinline__ unsigned pkbf(float x, float y) {
    __hip_bfloat162 h = __float22bfloat162_rn(make_float2(x, y));  // -> v_cvt_pk_bf16_f32
    return *(unsigned*)&h;
}

// ---------------- K1: GroupNorm stats: one block per (b,group) ----------------
__global__ void k_gnstats(const float* __restrict__ x, float* __restrict__ stats) {
    int bg = blockIdx.x;
    int t = threadIdx.x;
    const float4* b4 = (const float4*)(x + (size_t)bg * (8 * NSP));
    float s = 0.f, sq = 0.f;
    #pragma unroll
    for (int i = 0; i < 32; i++) {
        float4 v = b4[t + i * 256];
        s  += v.x + v.y + v.z + v.w;
        sq += v.x * v.x + v.y * v.y + v.z * v.z + v.w * v.w;
    }
    #pragma unroll
    for (int off = 32; off > 0; off >>= 1) {
        s  += __shfl_down(s, off);
        sq += __shfl_down(sq, off);
    }
    __shared__ float rs[4], rq[4];
    int w = t >> 6;
    if ((t & 63) == 0) { rs[w] = s; rq[w] = sq; }
    __syncthreads();
    if (t == 0) {
        float S = rs[0] + rs[1] + rs[2] + rs[3];
        float Q = rq[0] + rq[1] + rq[2] + rq[3];
        float mu  = S * (1.0f / 32768.0f);
        float var = Q * (1.0f / 32768.0f) - mu * mu;
        stats[bg * 2]     = mu;
        stats[bg * 2 + 1] = rsqrtf(var + EPS_GN);
    }
}

// ------ K2: apply GN, write xn^T (b,p,c) bf16, per-channel partial sums ------
__global__ void k_gnapply(const float* __restrict__ x, const float* __restrict__ gn_w,
                          const float* __restrict__ gn_b, const float* __restrict__ stats,
                          unsigned short* __restrict__ xnt, float* __restrict__ gpart) {
    int p0 = blockIdx.x * 64, c0 = blockIdx.y * 64, b = blockIdx.z;
    int t = threadIdx.x;
    __shared__ float tile[64][65];
    int ci0 = t >> 4, pq = t & 15;
    #pragma unroll
    for (int k = 0; k < 4; k++) {
        int ci = ci0 + k * 16;
        int c = c0 + ci;
        float mu   = stats[(b * GROUPS + (c >> 3)) * 2];
        float rstd = stats[(b * GROUPS + (c >> 3)) * 2 + 1];
        float w  = gn_w[c] * rstd;
        float bb = gn_b[c] - mu * w;
        float4 v = *(const float4*)(x + ((size_t)(b * CH + c)) * NSP + p0 + pq * 4);
        tile[ci][pq * 4 + 0] = v.x * w + bb;
        tile[ci][pq * 4 + 1] = v.y * w + bb;
        tile[ci][pq * 4 + 2] = v.z * w + bb;
        tile[ci][pq * 4 + 3] = v.w * w + bb;
    }
    __syncthreads();
    int pi = t >> 2, cb = (t & 3) * 16;
    unsigned pack[8];
    #pragma unroll
    for (int e = 0; e < 8; e++) {
        float a  = tile[cb + 2 * e][pi];
        float bv = tile[cb + 2 * e + 1][pi];
        pack[e] = (unsigned)f2bf(a) | ((unsigned)f2bf(bv) << 16);
    }
    uint4* dst = (uint4*)(xnt + ((size_t)(b * NSP + p0 + pi)) * CH + c0 + cb);
    dst[0] = make_uint4(pack[0], pack[1], pack[2], pack[3]);
    dst[1] = make_uint4(pack[4], pack[5], pack[6], pack[7]);
    if (t < 64) {
        float s = 0.f;
        #pragma unroll
        for (int j = 0; j < 64; j++) s += tile[t][j];
        gpart[((size_t)(b * CH + c0 + t)) * 64 + blockIdx.x] = s;
    }
}

// -------- K3: gfeat = mean(xn) @ gproj_w^T + gproj_b --------
__global__ void k_gproj(const float* __restrict__ gpart, const float* __restrict__ gproj_w,
                        const float* __restrict__ gproj_b, float* __restrict__ gfeat) {
    int b = blockIdx.x, t = threadIdx.x;
    __shared__ float graw[256];
    const float* p = gpart + ((size_t)(b * CH + t)) * 64;
    float s = 0.f;
    #pragma unroll
    for (int i = 0; i < 64; i++) s += p[i];
    graw[t] = s * (1.0f / 4096.0f);
    __syncthreads();
    float acc = gproj_b[t];
    const float* wr = gproj_w + (size_t)t * CH;
    #pragma unroll 8
    for (int c = 0; c < 256; c++) acc += graw[c] * wr[c];
    gfeat[b * CH + t] = acc;
}

// ---------------- K4: convert qkv_w + proj_w to bf16 ----------------
__global__ void k_convert(const float* __restrict__ qkv_w, const float* __restrict__ proj_w,
                          unsigned short* __restrict__ wbf) {
    int i4 = blockIdx.x * 256 + threadIdx.x;
    const float* src = (i4 < 49152) ? (qkv_w + (size_t)i4 * 4)
                                    : (proj_w + (size_t)(i4 - 49152) * 4);
    float4 v = *(const float4*)src;
    ushort4 o;
    o.x = f2bf(v.x); o.y = f2bf(v.y); o.z = f2bf(v.z); o.w = f2bf(v.w);
    *(ushort4*)(wbf + (size_t)i4 * 4) = o;
}

// ---------------- K5a: QKV GEMM -> bf16 q/k/v in attention layouts ----------------
__global__ void k_gemm_qkv(const unsigned short* __restrict__ Ag,
                           const unsigned short* __restrict__ Btg,
                           const float* __restrict__ bias,
                           const float* __restrict__ gfeat,
                           unsigned short* __restrict__ qt,
                           unsigned short* __restrict__ kt,
                           unsigned short* __restrict__ vt) {
    int n0 = blockIdx.x * 128, m0 = blockIdx.y * 64, b = blockIdx.z;
    int t = threadIdx.x, lane = t & 63, w = t >> 6;
    int wm = w >> 1, wn = w & 1;
    __shared__ short A_lds[64][40];
    __shared__ short B_lds[128][40];
    const unsigned short* Bb = Btg + (size_t)b * NSP * CH;
    f32x4 acc[2][4];
    #pragma unroll
    for (int m = 0; m < 2; m++)
        #pragma unroll
        for (int n = 0; n < 4; n++) acc[m][n] = (f32x4){0.f, 0.f, 0.f, 0.f};
    int arow = t >> 2, akk = (t & 3) * 8;
    for (int k0 = 0; k0 < 256; k0 += 32) {
        __syncthreads();
        *(uint4*)&A_lds[arow][akk] = *(const uint4*)(Ag + (size_t)(m0 + arow) * CH + k0 + akk);
        #pragma unroll
        for (int hh = 0; hh < 2; hh++) {
            int f = t + hh * 256;
            int j = f >> 2, kk = (f & 3) * 8;
            *(uint4*)&B_lds[j][kk] = *(const uint4*)(Bb + (size_t)(n0 + j) * CH + k0 + kk);
        }
        __syncthreads();
        short8 a[2], bf[4];
        #pragma unroll
        for (int m = 0; m < 2; m++)
            a[m] = *(const short8*)&A_lds[wm * 32 + m * 16 + (lane & 15)][(lane >> 4) * 8];
        #pragma unroll
        for (int n = 0; n < 4; n++)
            bf[n] = *(const short8*)&B_lds[wn * 64 + n * 16 + (lane & 15)][(lane >> 4) * 8];
        #pragma unroll
        for (int m = 0; m < 2; m++)
            #pragma unroll
            for (int n = 0; n < 4; n++)
                acc[m][n] = __builtin_amdgcn_mfma_f32_16x16x32_bf16(a[m], bf[n], acc[m][n], 0, 0, 0);
    }
    int rbase = m0 + wm * 32 + ((lane >> 4) << 2);
    int cbase = n0 + wn * 64 + (lane & 15);
    #pragma unroll
    for (int m = 0; m < 2; m++) {
        int row0 = rbase + m * 16;
        int sec = row0 >> 8;
        int ch  = row0 & 255;
        int h = ch >> 5, d0 = ch & 31;
        #pragma unroll
        for (int n = 0; n < 4; n++) {
            int col = cbase + n * 16;
            if (sec == 0) {
                ushort4 pk;
                pk.x = f2bf(acc[m][n][0] + bias[row0 + 0]);
                pk.y = f2bf(acc[m][n][1] + bias[row0 + 1]);
                pk.z = f2bf(acc[m][n][2] + bias[row0 + 2]);
                pk.w = f2bf(acc[m][n][3] + bias[row0 + 3]);
                *(ushort4*)(qt + ((size_t)((b * 8 + h) * NSP + col)) * HD + d0) = pk;
            } else if (sec == 1) {
                ushort4 pk;
                #pragma unroll
                for (int i = 0; i < 4; i++) {
                    float v = (acc[m][n][i] + bias[row0 + i]
                               + 0.1f * gfeat[b * CH + ch + i]) * ATT_SCALE;
                    ((unsigned short*)&pk)[i] = f2bf(v);
                }
                *(ushort4*)(kt + ((size_t)((b * 8 + h) * NSP + col)) * HD + d0) = pk;
            } else {
                #pragma unroll
                for (int i = 0; i < 4; i++) {
                    float v = acc[m][n][i] + bias[row0 + i];
                    vt[((size_t)((b * 8 + h) * HD + d0 + i)) * NSP + col] = f2bf(v);
                }
            }
        }
    }
}

// ---------------- K5b: proj GEMM (reads att bf16, adds residuals) ----------------
__global__ void k_gemm_proj(const unsigned short* __restrict__ Ag,
                            const unsigned short* __restrict__ Btg,
                            const float* __restrict__ bias,
                            const float* __restrict__ gfeat,
                            const float* __restrict__ xres,
                            float* __restrict__ out) {
    int n0 = blockIdx.x * 128, m0 = blockIdx.y * 64, b = blockIdx.z;
    int t = threadIdx.x, lane = t & 63, w = t >> 6;
    int wm = w >> 1, wn = w & 1;
    __shared__ short A_lds[64][40];
    __shared__ short B_lds[128][40];
    const unsigned short* Bb = Btg + (size_t)b * NSP * CH;
    f32x4 acc[2][4];
    #pragma unroll
    for (int m = 0; m < 2; m++)
        #pragma unroll
        for (int n = 0; n < 4; n++) acc[m][n] = (f32x4){0.f, 0.f, 0.f, 0.f};
    int arow = t >> 2, akk = (t & 3) * 8;
    for (int k0 = 0; k0 < 256; k0 += 32) {
        __syncthreads();
        *(uint4*)&A_lds[arow][akk] = *(const uint4*)(Ag + (size_t)(m0 + arow) * CH + k0 + akk);
        #pragma unroll
        for (int hh = 0; hh < 2; hh++) {
            int f = t + hh * 256;
            int j = f >> 2, kk = (f & 3) * 8;
            *(uint4*)&B_lds[j][kk] = *(const uint4*)(Bb + (size_t)(n0 + j) * CH + k0 + kk);
        }
        __syncthreads();
        short8 a[2], bf[4];
        #pragma unroll
        for (int m = 0; m < 2; m++)
            a[m] = *(const short8*)&A_lds[wm * 32 + m * 16 + (lane & 15)][(lane >> 4) * 8];
        #pragma unroll
        for (int n = 0; n < 4; n++)
            bf[n] = *(const short8*)&B_lds[wn * 64 + n * 16 + (lane & 15)][(lane >> 4) * 8];
        #pragma unroll
        for (int m = 0; m < 2; m++)
            #pragma unroll
            for (int n = 0; n < 4; n++)
                acc[m][n] = __builtin_amdgcn_mfma_f32_16x16x32_bf16(a[m], bf[n], acc[m][n], 0, 0, 0);
    }
    int rbase = m0 + wm * 32 + ((lane >> 4) << 2);
    int cbase = n0 + wn * 64 + (lane & 15);
    #pragma unroll
    for (int m = 0; m < 2; m++) {
        #pragma unroll
        for (int n = 0; n < 4; n++) {
            int col = cbase + n * 16;
            #pragma unroll
            for (int i = 0; i < 4; i++) {
                int row = rbase + m * 16 + i;
                float add = bias[row] + 0.1f * gfeat[b * CH + row]
                          + xres[((size_t)(b * CH + row)) * NSP + col];
                out[((size_t)(b * CH + row)) * NSP + col] = acc[m][n][i] + add;
            }
        }
    }
}

// ------------- K6: 32x32 MFMA flash attention, in-register P, split-KV -------------
// blockIdx.x = qtile(0..31) + 32*split. 4 waves x 32 q-rows = 128 q per block; KV tile 64.
// S^T = mfma(K,Q) 32x32x16 x2 (chained over d): lane holds S[j][q=lane&31],
//   j = jt*32 + (r&3) + 8*(r>>2) + 4*hi  (r = acc reg, hi = lane>>5).
// P stays in registers: cvt_pk pairs + shfl_xor(32) build PV B-frags (T12).
// O^T = mfma(V,P): lane holds O[d=(r&3)+8*(r>>2)+4*hi][q=lane&31].
// Partials: opart bf16 [s][b][h][q][d] (unnormalized), lmpart fp32 {m,l}.
__global__ __launch_bounds__(256)
void k_flash32(const unsigned short* __restrict__ qt,
               const unsigned short* __restrict__ kt,
               const unsigned short* __restrict__ vt,
               unsigned short* __restrict__ opart, float* __restrict__ lmpart) {
    const int h = blockIdx.y, b = blockIdx.z;
    const int s = blockIdx.x >> 5;
    const int t = threadIdx.x, lane = t & 63, w = t >> 6;
    const int lo32 = lane & 31, hi = lane >> 5;
    const int q0 = (blockIdx.x & 31) * 128 + w * 32;
    const int j0base = s * (NSP / NSPLIT);
    const unsigned short* qp = qt + ((size_t)(b * 8 + h) * NSP) * HD;
    const unsigned short* kp = kt + ((size_t)(b * 8 + h) * NSP) * HD;
    const unsigned short* vp = vt + ((size_t)(b * 8 + h) * HD) * NSP;
    // XOR-swizzled 16B slots: K[j][d]: slot^(j&3); V[d][j]: slot^(d&7)
    __shared__ __align__(16) unsigned short K_lds[64 * 32];
    __shared__ __align__(16) unsigned short V_lds[32 * 64];

    // Q B-frags (held whole kernel): mfma k-half c: d = c*16 + hi*8
    short8 qf0 = *(const short8*)(qp + (size_t)(q0 + lo32) * HD + hi * 8);
    short8 qf1 = *(const short8*)(qp + (size_t)(q0 + lo32) * HD + 16 + hi * 8);
    f32x16 oacc;
    #pragma unroll
    for (int i = 0; i < 16; i++) oacc[i] = 0.f;
    float m = -1e30f, l = 0.f;

    // staging: 256 threads x 16B = one 4KB tile each for K and V
    const int kj = t >> 2, kslot = t & 3;
    const int vd = t >> 3, vslot = t & 7;
    const unsigned short* kga = kp + (size_t)(j0base + kj) * HD + kslot * 8;
    const unsigned short* vga = vp + (size_t)vd * NSP + j0base + vslot * 8;
    uint4 kreg = *(const uint4*)kga;
    uint4 vreg = *(const uint4*)vga;
    const int kws = kj * 32 + ((kslot ^ (kj & 3)) * 8);
    const int vws = vd * 64 + ((vslot ^ (vd & 7)) * 8);

    const int NT = NSP / NSPLIT / 64;
    for (int it = 0; it < NT; ++it) {
        *(uint4*)&K_lds[kws] = kreg;
        *(uint4*)&V_lds[vws] = vreg;
        __syncthreads();
        if (it + 1 < NT) {   // T14: issue next-tile loads; land under compute
            kreg = *(const uint4*)(kga + (size_t)(it + 1) * 64 * HD);
            vreg = *(const uint4*)(vga + (it + 1) * 64);
        }
        // ---- S^T = K Q^T : two 32x32 tiles, K=32 chained as 2x k16 ----
        const int jA = lo32, jB = 32 + lo32;
        short8 k00 = *(const short8*)&K_lds[jA * 32 + (((0 + hi) ^ (jA & 3)) * 8)];
        short8 k01 = *(const short8*)&K_lds[jA * 32 + (((2 + hi) ^ (jA & 3)) * 8)];
        short8 k10 = *(const short8*)&K_lds[jB * 32 + (((0 + hi) ^ (jB & 3)) * 8)];
        short8 k11 = *(const short8*)&K_lds[jB * 32 + (((2 + hi) ^ (jB & 3)) * 8)];
        f32x16 sv0, sv1;
        __builtin_amdgcn_s_setprio(1);
        sv0 = __builtin_amdgcn_mfma_f32_32x32x16_bf16(k00, qf0, ZERO16, 0, 0, 0);
        sv0 = __builtin_amdgcn_mfma_f32_32x32x16_bf16(k01, qf1, sv0, 0, 0, 0);
        sv1 = __builtin_amdgcn_mfma_f32_32x32x16_bf16(k10, qf0, ZERO16, 0, 0, 0);
        sv1 = __builtin_amdgcn_mfma_f32_32x32x16_bf16(k11, qf1, sv1, 0, 0, 0);
        __builtin_amdgcn_s_setprio(0);
        // ---- per-lane row max over 32 local + partner exchange ----
        float a0 = fmaxf(fmaxf(sv0[0], sv0[1]), fmaxf(sv0[2], sv0[3]));
        float a1 = fmaxf(fmaxf(sv0[4], sv0[5]), fmaxf(sv0[6], sv0[7]));
        float a2 = fmaxf(fmaxf(sv0[8], sv0[9]), fmaxf(sv0[10], sv0[11]));
        float a3 = fmaxf(fmaxf(sv0[12], sv0[13]), fmaxf(sv0[14], sv0[15]));
        float a4 = fmaxf(fmaxf(sv1[0], sv1[1]), fmaxf(sv1[2], sv1[3]));
        float a5 = fmaxf(fmaxf(sv1[4], sv1[5]), fmaxf(sv1[6], sv1[7]));
        float a6 = fmaxf(fmaxf(sv1[8], sv1[9]), fmaxf(sv1[10], sv1[11]));
        float a7 = fmaxf(fmaxf(sv1[12], sv1[13]), fmaxf(sv1[14], sv1[15]));
        float vmx = fmaxf(fmaxf(fmaxf(a0, a1), fmaxf(a2, a3)),
                          fmaxf(fmaxf(a4, a5), fmaxf(a6, a7)));
        vmx = fmaxf(vmx, __shfl_xor(vmx, 32));
        // ---- T13 defer-max: rescale only when max grew by > 8 (log2 units) ----
        if (__any(vmx > m + 8.f)) {
            float nm = fmaxf(m, vmx);
            float corr = __builtin_amdgcn_exp2f(m - nm);
            m = nm;
            l *= corr;
            #pragma unroll
            for (int i = 0; i < 16; i++) oacc[i] *= corr;
        }
        #pragma unroll
        for (int i = 0; i < 16; i++) {
            sv0[i] = __builtin_amdgcn_exp2f(sv0[i] - m);
            sv1[i] = __builtin_amdgcn_exp2f(sv1[i] - m);
        }
        float sm = (((sv0[0] + sv0[1]) + (sv0[2] + sv0[3])) + ((sv0[4] + sv0[5]) + (sv0[6] + sv0[7])))
                 + (((sv0[8] + sv0[9]) + (sv0[10] + sv0[11])) + ((sv0[12] + sv0[13]) + (sv0[14] + sv0[15])))
                 + (((sv1[0] + sv1[1]) + (sv1[2] + sv1[3])) + ((sv1[4] + sv1[5]) + (sv1[6] + sv1[7])))
                 + (((sv1[8] + sv1[9]) + (sv1[10] + sv1[11])) + ((sv1[12] + sv1[13]) + (sv1[14] + sv1[15])));
        sm += __shfl_xor(sm, 32);
        l += sm;
        // ---- P->bf16 in-register + partner exchange; O^T += V P ----
        // per PV mfma c (k = j = c*16 + hi*8 + 0..7):
        //   hi=0 frag: {own p0,p1 (j b+0..3), partner p0,p1 (j b+4..7)}
        //   hi=1 frag: {partner p2,p3 (j b+8..11), own p2,p3 (j b+12..15)}
        #define PVSTEP(SV, BB, C) { \
            unsigned p0 = pkbf(SV[BB + 0], SV[BB + 1]); \
            unsigned p1 = pkbf(SV[BB + 2], SV[BB + 3]); \
            unsigned p2 = pkbf(SV[BB + 4], SV[BB + 5]); \
            unsigned p3 = pkbf(SV[BB + 6], SV[BB + 7]); \
            unsigned s0 = hi ? p0 : p2, s1 = hi ? p1 : p3; \
            unsigned r0 = __shfl_xor(s0, 32), r1 = __shfl_xor(s1, 32); \
            uint4 fu = hi ? make_uint4(r0, r1, p2, p3) : make_uint4(p0, p1, r0, r1); \
            short8 pa = *(short8*)&fu; \
            short8 vf = *(const short8*)&V_lds[lo32 * 64 + ((((C) * 2 + hi) ^ (lo32 & 7)) * 8)]; \
            oacc = __builtin_amdgcn_mfma_f32_32x32x16_bf16(vf, pa, oacc, 0, 0, 0); \
        }
        __builtin_amdgcn_s_setprio(1);
        PVSTEP(sv0, 0, 0)
        PVSTEP(sv0, 8, 1)
        PVSTEP(sv1, 0, 2)
        PVSTEP(sv1, 8, 3)
        __builtin_amdgcn_s_setprio(0);
        #undef PVSTEP
        __syncthreads();   // protect K_lds/V_lds before next stage
    }
    // bf16 unnormalized partials: lane q = q0+lo32, d = 8*rr + 4*hi + 0..3
    unsigned short* op = opart + ((((size_t)s * BATCH + b) * HEADS + h) * NSP + q0 + lo32) * HD;
    #pragma unroll
    for (int rr = 0; rr < 4; rr++) {
        ushort4 pk4;
        pk4.x = f2bf(oacc[rr * 4 + 0]);
        pk4.y = f2bf(oacc[rr * 4 + 1]);
        pk4.z = f2bf(oacc[rr * 4 + 2]);
        pk4.w = f2bf(oacc[rr * 4 + 3]);
        *(ushort4*)(op + rr * 8 + hi * 4) = pk4;
    }
    if (hi == 0)
        *(float2*)(lmpart + ((((size_t)s * BATCH + b) * HEADS + h) * NSP + q0 + lo32) * 2)
            = make_float2(m, l);
}

// ------------- K7: combine NSPLIT partials -> att bf16 (b,p,c) -------------
__global__ __launch_bounds__(256)
void k_combine(const unsigned short* __restrict__ opart, const float* __restrict__ lmpart,
               unsigned short* __restrict__ att) {
    int flat = blockIdx.x * 256 + threadIdx.x;   // 2*8*4096*4 = 262144
    int dchunk = flat & 3;
    int q = (flat >> 2) & (NSP - 1);
    int bh = flat >> 14;
    const size_t sO = (size_t)BATCH * HEADS * NSP * HD;
    const size_t sL = (size_t)BATCH * HEADS * NSP * 2;
    size_t rowq = (size_t)bh * NSP + q;
    float2 lm[NSPLIT];
    float M = -1e30f;
    #pragma unroll
    for (int s2 = 0; s2 < NSPLIT; s2++) {
        lm[s2] = *(const float2*)(lmpart + s2 * sL + rowq * 2);
        M = fmaxf(M, lm[s2].x);
    }
    float den = 0.f, cw[NSPLIT];
    #pragma unroll
    for (int s2 = 0; s2 < NSPLIT; s2++) {
        cw[s2] = __builtin_amdgcn_exp2f(lm[s2].x - M);
        den += lm[s2].y * cw[s2];
    }
    float inv = 1.0f / den;
    float acc[8];
    #pragma unroll
    for (int e = 0; e < 8; e++) acc[e] = 0.f;
    #pragma unroll
    for (int s2 = 0; s2 < NSPLIT; s2++) {
        uint4 v = *(const uint4*)(opart + s2 * sO + rowq * HD + dchunk * 8);
        float wgt = cw[s2] * inv;
        const unsigned short* pv = (const unsigned short*)&v;
        #pragma unroll
        for (int e = 0; e < 8; e++) {
            unsigned u = (unsigned)pv[e] << 16;
            acc[e] += wgt * *(float*)&u;
        }
    }
    uint4 o;
    o.x = (unsigned)f2bf(acc[0]) | ((unsigned)f2bf(acc[1]) << 16);
    o.y = (unsigned)f2bf(acc[2]) | ((unsigned)f2bf(acc[3]) << 16);
    o.z = (unsigned)f2bf(acc[4]) | ((unsigned)f2bf(acc[5]) << 16);
    o.w = (unsigned)f2bf(acc[6]) | ((unsigned)f2bf(acc[7]) << 16);
    *(uint4*)(att + ((size_t)((bh >> 3) * NSP + q)) * CH + (bh & 7) * HD + dchunk * 8) = o;
}

extern "C" void kernel_launch(void* const* d_in, const int* in_sizes, int n_in,
                              void* d_out, int out_size, void* d_ws, size_t ws_size,
                              hipStream_t stream) {
    const float* x       = (const float*)d_in[0];
    const float* gn_w    = (const float*)d_in[1];
    const float* gn_b    = (const float*)d_in[2];
    const float* qkv_w   = (const float*)d_in[3];
    const float* qkv_b   = (const float*)d_in[4];
    const float* proj_w  = (const float*)d_in[5];
    const float* proj_b  = (const float*)d_in[6];
    const float* gproj_w = (const float*)d_in[7];
    const float* gproj_b = (const float*)d_in[8];
    char* ws = (char*)d_ws;
    float*          stats  = (float*)(ws);                      // 512 B
    float*          gpart  = (float*)(ws + 1024);               // 128 KB
    float*          gfeat  = (float*)(ws + 132096);             // 2 KB
    unsigned short* wbf    = (unsigned short*)(ws + 134144);    // 512 KB bf16 weights
    unsigned short* xnt    = (unsigned short*)(ws + 658432);    // (b,p,c) bf16, 4 MB (dead after qkv GEMM)
    float*          lmpart = (float*)(ws + 658432);             // overlays xnt: 2 MB {m,l}
    unsigned short* qt     = (unsigned short*)(ws + 4852736);   // (b,h,n,hd) bf16, 4 MB
    unsigned short* kt     = (unsigned short*)(ws + 9047040);   // (b,h,n,hd) bf16, 4 MB
    unsigned short* vt     = (unsigned short*)(ws + 13241344);  // (b,h,hd,n) bf16, 4 MB
    unsigned short* att    = (unsigned short*)(ws + 17435648);  // (b,p,c) bf16, 4 MB
    unsigned short* opart  = (unsigned short*)(ws + 21629952);  // 4 splits bf16 O, 16.8 MB
    float* out = (float*)d_out;

    hipLaunchKernelGGL(k_gnstats, dim3(64), dim3(256), 0, stream, x, stats);
    hipLaunchKernelGGL(k_gnapply, dim3(64, 4, 2), dim3(256), 0, stream,
                       x, gn_w, gn_b, stats, xnt, gpart);
    hipLaunchKernelGGL(k_gproj, dim3(2), dim3(256), 0, stream,
                       gpart, gproj_w, gproj_b, gfeat);
    hipLaunchKernelGGL(k_convert, dim3(256), dim3(256), 0, stream, qkv_w, proj_w, wbf);
    hipLaunchKernelGGL(k_gemm_qkv, dim3(32, 12, 2), dim3(256), 0, stream,
                       wbf, xnt, qkv_b, gfeat, qt, kt, vt);
    hipLaunchKernelGGL(k_flash32, dim3(32 * NSPLIT, 8, 2), dim3(256), 0, stream,
                       qt, kt, vt, opart, lmpart);
    hipLaunchKernelGGL(k_combine, dim3(1024), dim3(256), 0, stream,
                       opart, lmpart, att);
    hipLaunchKernelGGL(k_gemm_proj, dim3(32, 4, 2), dim3(256), 0, stream,
                       wbf + 196608, att, proj_b, gfeat, x, out);
}

// Round 8
// 126.853 us; speedup vs baseline: 13.2148x; 1.0471x over previous
//
#include <hip/hip_runtime.h>
#include <hip/hip_bf16.h>
#include <stdint.h>

#define BATCH 2
#define CH 256
#define NSP 4096          // 64*64 spatial
#define HEADS 8
#define HD 32
#define GROUPS 32
#define EPS_GN 1e-5f
#define NSPLIT 4          // flash KV-sequence splits

// hd^-0.5 * log2(e): folds softmax scale AND exp->exp2 conversion into k
#define ATT_SCALE (0.17677669529663687f * 1.4426950408889634f)

typedef __attribute__((ext_vector_type(8))) short short8;    // 8 bf16 (MFMA A/B frag)
typedef __attribute__((ext_vector_type(4))) float f32x4;     // 16x16 C/D frag
typedef __attribute__((ext_vector_type(16))) float f32x16;   // 32x32 C/D frag
typedef __attribute__((ext_vector_type(2))) float f32x2;     // v_pk_add_f32 operand

#define ZERO16 ((f32x16){0.f,0.f,0.f,0.f,0.f,0.f,0.f,0.f,0.f,0.f,0.f,0.f,0.f,0.f,0.f,0.f})

static __device__ __forceinline__ unsigned short f2bf(float f) {
    union { float f; unsigned u; } v; v.f = f;
    unsigned r = v.u + 0x7fffu + ((v.u >> 16) & 1u);  // RNE
    return (unsigned short)(r >> 16);
}
static __device__ __forceinline__ unsigned pkbf(float x, float y) {
    __hip_bfloat162 h = __float22bfloat162_rn(make_float2(x, y));  // -> v_cvt_pk_bf16_f32
    return *(unsigned*)&h;
}

// ---------------- K1: GroupNorm stats: one block per (b,group) ----------------
__global__ void k_gnstats(const float* __restrict__ x, float* __restrict__ stats) {
    int bg = blockIdx.x;
    int t = threadIdx.x;
    const float4* b4 = (const float4*)(x + (size_t)bg * (8 * NSP));
    float s = 0.f, sq = 0.f;
    #pragma unroll
    for (int i = 0; i < 32; i++) {
        float4 v = b4[t + i * 256];
        s  += v.x + v.y + v.z + v.w;
        sq += v.x * v.x + v.y * v.y + v.z * v.z + v.w * v.w;
    }
    #pragma unroll
    for (int off = 32; off > 0; off >>= 1) {
        s  += __shfl_down(s, off);
        sq += __shfl_down(sq, off);
    }
    __shared__ float rs[4], rq[4];
    int w = t >> 6;
    if ((t & 63) == 0) { rs[w] = s; rq[w] = sq; }
    __syncthreads();
    if (t == 0) {
        float S = rs[0] + rs[1] + rs[2] + rs[3];
        float Q = rq[0] + rq[1] + rq[2] + rq[3];
        float mu  = S * (1.0f / 32768.0f);
        float var = Q * (1.0f / 32768.0f) - mu * mu;
        stats[bg * 2]     = mu;
        stats[bg * 2 + 1] = rsqrtf(var + EPS_GN);
    }
}

// ------ K2: apply GN, write xn^T (b,p,c) bf16, per-channel partial sums ------
__global__ void k_gnapply(const float* __restrict__ x, const float* __restrict__ gn_w,
                          const float* __restrict__ gn_b, const float* __restrict__ stats,
                          unsigned short* __restrict__ xnt, float* __restrict__ gpart) {
    int p0 = blockIdx.x * 64, c0 = blockIdx.y * 64, b = blockIdx.z;
    int t = threadIdx.x;
    __shared__ float tile[64][65];
    int ci0 = t >> 4, pq = t & 15;
    #pragma unroll
    for (int k = 0; k < 4; k++) {
        int ci = ci0 + k * 16;
        int c = c0 + ci;
        float mu   = stats[(b * GROUPS + (c >> 3)) * 2];
        float rstd = stats[(b * GROUPS + (c >> 3)) * 2 + 1];
        float w  = gn_w[c] * rstd;
        float bb = gn_b[c] - mu * w;
        float4 v = *(const float4*)(x + ((size_t)(b * CH + c)) * NSP + p0 + pq * 4);
        tile[ci][pq * 4 + 0] = v.x * w + bb;
        tile[ci][pq * 4 + 1] = v.y * w + bb;
        tile[ci][pq * 4 + 2] = v.z * w + bb;
        tile[ci][pq * 4 + 3] = v.w * w + bb;
    }
    __syncthreads();
    int pi = t >> 2, cb = (t & 3) * 16;
    unsigned pack[8];
    #pragma unroll
    for (int e = 0; e < 8; e++) {
        float a  = tile[cb + 2 * e][pi];
        float bv = tile[cb + 2 * e + 1][pi];
        pack[e] = (unsigned)f2bf(a) | ((unsigned)f2bf(bv) << 16);
    }
    uint4* dst = (uint4*)(xnt + ((size_t)(b * NSP + p0 + pi)) * CH + c0 + cb);
    dst[0] = make_uint4(pack[0], pack[1], pack[2], pack[3]);
    dst[1] = make_uint4(pack[4], pack[5], pack[6], pack[7]);
    if (t < 64) {
        float s = 0.f;
        #pragma unroll
        for (int j = 0; j < 64; j++) s += tile[t][j];
        gpart[((size_t)(b * CH + c0 + t)) * 64 + blockIdx.x] = s;
    }
}

// -------- K3: gfeat = mean(xn) @ gproj_w^T + gproj_b --------
__global__ void k_gproj(const float* __restrict__ gpart, const float* __restrict__ gproj_w,
                        const float* __restrict__ gproj_b, float* __restrict__ gfeat) {
    int b = blockIdx.x, t = threadIdx.x;
    __shared__ float graw[256];
    const float* p = gpart + ((size_t)(b * CH + t)) * 64;
    float s = 0.f;
    #pragma unroll
    for (int i = 0; i < 64; i++) s += p[i];
    graw[t] = s * (1.0f / 4096.0f);
    __syncthreads();
    float acc = gproj_b[t];
    const float* wr = gproj_w + (size_t)t * CH;
    #pragma unroll 8
    for (int c = 0; c < 256; c++) acc += graw[c] * wr[c];
    gfeat[b * CH + t] = acc;
}

// ---------------- K4: convert qkv_w + proj_w to bf16 ----------------
__global__ void k_convert(const float* __restrict__ qkv_w, const float* __restrict__ proj_w,
                          unsigned short* __restrict__ wbf) {
    int i4 = blockIdx.x * 256 + threadIdx.x;
    const float* src = (i4 < 49152) ? (qkv_w + (size_t)i4 * 4)
                                    : (proj_w + (size_t)(i4 - 49152) * 4);
    float4 v = *(const float4*)src;
    ushort4 o;
    o.x = f2bf(v.x); o.y = f2bf(v.y); o.z = f2bf(v.z); o.w = f2bf(v.w);
    *(ushort4*)(wbf + (size_t)i4 * 4) = o;
}

// ---------------- K5a: QKV GEMM -> bf16 q/k/v in attention layouts ----------------
__global__ void k_gemm_qkv(const unsigned short* __restrict__ Ag,
                           const unsigned short* __restrict__ Btg,
                           const float* __restrict__ bias,
                           const float* __restrict__ gfeat,
                           unsigned short* __restrict__ qt,
                           unsigned short* __restrict__ kt,
                           unsigned short* __restrict__ vt) {
    int n0 = blockIdx.x * 128, m0 = blockIdx.y * 64, b = blockIdx.z;
    int t = threadIdx.x, lane = t & 63, w = t >> 6;
    int wm = w >> 1, wn = w & 1;
    __shared__ short A_lds[64][40];
    __shared__ short B_lds[128][40];
    const unsigned short* Bb = Btg + (size_t)b * NSP * CH;
    f32x4 acc[2][4];
    #pragma unroll
    for (int m = 0; m < 2; m++)
        #pragma unroll
        for (int n = 0; n < 4; n++) acc[m][n] = (f32x4){0.f, 0.f, 0.f, 0.f};
    int arow = t >> 2, akk = (t & 3) * 8;
    for (int k0 = 0; k0 < 256; k0 += 32) {
        __syncthreads();
        *(uint4*)&A_lds[arow][akk] = *(const uint4*)(Ag + (size_t)(m0 + arow) * CH + k0 + akk);
        #pragma unroll
        for (int hh = 0; hh < 2; hh++) {
            int f = t + hh * 256;
            int j = f >> 2, kk = (f & 3) * 8;
            *(uint4*)&B_lds[j][kk] = *(const uint4*)(Bb + (size_t)(n0 + j) * CH + k0 + kk);
        }
        __syncthreads();
        short8 a[2], bf[4];
        #pragma unroll
        for (int m = 0; m < 2; m++)
            a[m] = *(const short8*)&A_lds[wm * 32 + m * 16 + (lane & 15)][(lane >> 4) * 8];
        #pragma unroll
        for (int n = 0; n < 4; n++)
            bf[n] = *(const short8*)&B_lds[wn * 64 + n * 16 + (lane & 15)][(lane >> 4) * 8];
        #pragma unroll
        for (int m = 0; m < 2; m++)
            #pragma unroll
            for (int n = 0; n < 4; n++)
                acc[m][n] = __builtin_amdgcn_mfma_f32_16x16x32_bf16(a[m], bf[n], acc[m][n], 0, 0, 0);
    }
    int rbase = m0 + wm * 32 + ((lane >> 4) << 2);
    int cbase = n0 + wn * 64 + (lane & 15);
    #pragma unroll
    for (int m = 0; m < 2; m++) {
        int row0 = rbase + m * 16;
        int sec = row0 >> 8;
        int ch  = row0 & 255;
        int h = ch >> 5, d0 = ch & 31;
        #pragma unroll
        for (int n = 0; n < 4; n++) {
            int col = cbase + n * 16;
            if (sec == 0) {
                ushort4 pk;
                pk.x = f2bf(acc[m][n][0] + bias[row0 + 0]);
                pk.y = f2bf(acc[m][n][1] + bias[row0 + 1]);
                pk.z = f2bf(acc[m][n][2] + bias[row0 + 2]);
                pk.w = f2bf(acc[m][n][3] + bias[row0 + 3]);
                *(ushort4*)(qt + ((size_t)((b * 8 + h) * NSP + col)) * HD + d0) = pk;
            } else if (sec == 1) {
                ushort4 pk;
                #pragma unroll
                for (int i = 0; i < 4; i++) {
                    float v = (acc[m][n][i] + bias[row0 + i]
                               + 0.1f * gfeat[b * CH + ch + i]) * ATT_SCALE;
                    ((unsigned short*)&pk)[i] = f2bf(v);
                }
                *(ushort4*)(kt + ((size_t)((b * 8 + h) * NSP + col)) * HD + d0) = pk;
            } else {
                #pragma unroll
                for (int i = 0; i < 4; i++) {
                    float v = acc[m][n][i] + bias[row0 + i];
                    vt[((size_t)((b * 8 + h) * HD + d0 + i)) * NSP + col] = f2bf(v);
                }
            }
        }
    }
}

// ---------------- K5b: proj GEMM (reads att bf16, adds residuals) ----------------
__global__ void k_gemm_proj(const unsigned short* __restrict__ Ag,
                            const unsigned short* __restrict__ Btg,
                            const float* __restrict__ bias,
                            const float* __restrict__ gfeat,
                            const float* __restrict__ xres,
                            float* __restrict__ out) {
    int n0 = blockIdx.x * 128, m0 = blockIdx.y * 64, b = blockIdx.z;
    int t = threadIdx.x, lane = t & 63, w = t >> 6;
    int wm = w >> 1, wn = w & 1;
    __shared__ short A_lds[64][40];
    __shared__ short B_lds[128][40];
    const unsigned short* Bb = Btg + (size_t)b * NSP * CH;
    f32x4 acc[2][4];
    #pragma unroll
    for (int m = 0; m < 2; m++)
        #pragma unroll
        for (int n = 0; n < 4; n++) acc[m][n] = (f32x4){0.f, 0.f, 0.f, 0.f};
    int arow = t >> 2, akk = (t & 3) * 8;
    for (int k0 = 0; k0 < 256; k0 += 32) {
        __syncthreads();
        *(uint4*)&A_lds[arow][akk] = *(const uint4*)(Ag + (size_t)(m0 + arow) * CH + k0 + akk);
        #pragma unroll
        for (int hh = 0; hh < 2; hh++) {
            int f = t + hh * 256;
            int j = f >> 2, kk = (f & 3) * 8;
            *(uint4*)&B_lds[j][kk] = *(const uint4*)(Bb + (size_t)(n0 + j) * CH + k0 + kk);
        }
        __syncthreads();
        short8 a[2], bf[4];
        #pragma unroll
        for (int m = 0; m < 2; m++)
            a[m] = *(const short8*)&A_lds[wm * 32 + m * 16 + (lane & 15)][(lane >> 4) * 8];
        #pragma unroll
        for (int n = 0; n < 4; n++)
            bf[n] = *(const short8*)&B_lds[wn * 64 + n * 16 + (lane & 15)][(lane >> 4) * 8];
        #pragma unroll
        for (int m = 0; m < 2; m++)
            #pragma unroll
            for (int n = 0; n < 4; n++)
                acc[m][n] = __builtin_amdgcn_mfma_f32_16x16x32_bf16(a[m], bf[n], acc[m][n], 0, 0, 0);
    }
    int rbase = m0 + wm * 32 + ((lane >> 4) << 2);
    int cbase = n0 + wn * 64 + (lane & 15);
    #pragma unroll
    for (int m = 0; m < 2; m++) {
        #pragma unroll
        for (int n = 0; n < 4; n++) {
            int col = cbase + n * 16;
            #pragma unroll
            for (int i = 0; i < 4; i++) {
                int row = rbase + m * 16 + i;
                float add = bias[row] + 0.1f * gfeat[b * CH + row]
                          + xres[((size_t)(b * CH + row)) * NSP + col];
                out[((size_t)(b * CH + row)) * NSP + col] = acc[m][n][i] + add;
            }
        }
    }
}

// ------------- K6: 32x32 MFMA flash attention, in-register P, split-KV -------------
// S^T = mfma(K,Q): lane holds S[j][q=lane&31], j = jt*32 + (r&3) + 8*(r>>2) + 4*hi.
// P stays in registers: cvt_pk pairs + shfl_xor(32) build PV B-frags (T12).
// O^T = mfma(V,P): lane holds O[d=(r&3)+8*(r>>2)+4*hi][q=lane&31].
// K_lds rows padded to 80B (20 banks): 8-lane phases tile all 32 banks -> conflict-free.
// All cross-lane exchanges via __shfl_xor (r5-proven; permlane asm was the r6/r7 bug).
__global__ __launch_bounds__(256)
void k_flash32(const unsigned short* __restrict__ qt,
               const unsigned short* __restrict__ kt,
               const unsigned short* __restrict__ vt,
               unsigned short* __restrict__ opart, float* __restrict__ lmpart) {
    const int h = blockIdx.y, b = blockIdx.z;
    const int s = blockIdx.x >> 5;
    const int t = threadIdx.x, lane = t & 63, w = t >> 6;
    const int lo32 = lane & 31, hi = lane >> 5;
    const int q0 = (blockIdx.x & 31) * 128 + w * 32;
    const int j0base = s * (NSP / NSPLIT);
    const unsigned short* qp = qt + ((size_t)(b * 8 + h) * NSP) * HD;
    const unsigned short* kp = kt + ((size_t)(b * 8 + h) * NSP) * HD;
    const unsigned short* vp = vt + ((size_t)(b * 8 + h) * HD) * NSP;
    __shared__ __align__(16) unsigned short K_lds[64 * 40];   // 80B rows, conflict-free
    __shared__ __align__(16) unsigned short V_lds[32 * 64];   // 128B rows, XOR slot swizzle

    short8 qf0 = *(const short8*)(qp + (size_t)(q0 + lo32) * HD + hi * 8);
    short8 qf1 = *(const short8*)(qp + (size_t)(q0 + lo32) * HD + 16 + hi * 8);
    f32x16 oacc;
    #pragma unroll
    for (int i = 0; i < 16; i++) oacc[i] = 0.f;
    float m = -1e30f, l = 0.f;

    // staging: K remapped so 8-lane phases hit rows 0-7 (bank-tiling); 1KB-coalesced/wave
    const int krow = (t & 7) + 8 * (t >> 5);
    const int kslot = (t >> 3) & 3;
    const int vd = t >> 3, vslot = t & 7;
    const unsigned short* kga = kp + (size_t)(j0base + krow) * HD + kslot * 8;
    const unsigned short* vga = vp + (size_t)vd * NSP + j0base + vslot * 8;
    uint4 kreg = *(const uint4*)kga;
    uint4 vreg = *(const uint4*)vga;
    const int kws = krow * 40 + kslot * 8;
    const int vws = vd * 64 + ((vslot ^ (vd & 7)) * 8);

    const int NT = NSP / NSPLIT / 64;
    for (int it = 0; it < NT; ++it) {
        *(uint4*)&K_lds[kws] = kreg;
        *(uint4*)&V_lds[vws] = vreg;
        __syncthreads();
        if (it + 1 < NT) {   // T14: issue next-tile loads; land under compute
            kreg = *(const uint4*)(kga + (size_t)(it + 1) * 64 * HD);
            vreg = *(const uint4*)(vga + (it + 1) * 64);
        }
        // ---- S^T = K Q^T : two 32x32 tiles, K=32 chained as 2x k16 ----
        const int jA = lo32, jB = 32 + lo32;
        short8 k00 = *(const short8*)&K_lds[jA * 40 + hi * 8];
        short8 k01 = *(const short8*)&K_lds[jA * 40 + (2 + hi) * 8];
        short8 k10 = *(const short8*)&K_lds[jB * 40 + hi * 8];
        short8 k11 = *(const short8*)&K_lds[jB * 40 + (2 + hi) * 8];
        f32x16 sv0, sv1;
        __builtin_amdgcn_s_setprio(1);
        sv0 = __builtin_amdgcn_mfma_f32_32x32x16_bf16(k00, qf0, ZERO16, 0, 0, 0);
        sv0 = __builtin_amdgcn_mfma_f32_32x32x16_bf16(k01, qf1, sv0, 0, 0, 0);
        sv1 = __builtin_amdgcn_mfma_f32_32x32x16_bf16(k10, qf0, ZERO16, 0, 0, 0);
        sv1 = __builtin_amdgcn_mfma_f32_32x32x16_bf16(k11, qf1, sv1, 0, 0, 0);
        __builtin_amdgcn_s_setprio(0);
        // ---- row max: v_max3 triples + shfl partner exchange ----
        float h0 = fmaxf(fmaxf(sv0[0],  sv0[1]),  sv0[2]);
        float h1 = fmaxf(fmaxf(sv0[3],  sv0[4]),  sv0[5]);
        float h2 = fmaxf(fmaxf(sv0[6],  sv0[7]),  sv0[8]);
        float h3 = fmaxf(fmaxf(sv0[9],  sv0[10]), sv0[11]);
        float h4 = fmaxf(fmaxf(sv0[12], sv0[13]), sv0[14]);
        float h5 = fmaxf(fmaxf(sv1[0],  sv1[1]),  sv1[2]);
        float h6 = fmaxf(fmaxf(sv1[3],  sv1[4]),  sv1[5]);
        float h7 = fmaxf(fmaxf(sv1[6],  sv1[7]),  sv1[8]);
        float h8 = fmaxf(fmaxf(sv1[9],  sv1[10]), sv1[11]);
        float h9 = fmaxf(fmaxf(sv1[12], sv1[13]), sv1[14]);
        float r0 = fmaxf(fmaxf(h0, h1), h2);
        float r1 = fmaxf(fmaxf(h3, h4), h5);
        float r2 = fmaxf(fmaxf(h6, h7), h8);
        float r3 = fmaxf(fmaxf(h9, sv0[15]), sv1[15]);
        float vmx = fmaxf(fmaxf(r0, r1), fmaxf(r2, r3));
        vmx = fmaxf(vmx, __shfl_xor(vmx, 32));
        // ---- T13 defer-max: rescale only when max grew by > 8 (log2 units) ----
        if (__any(vmx > m + 8.f)) {
            float nm = fmaxf(m, vmx);
            float corr = __builtin_amdgcn_exp2f(m - nm);
            m = nm;
            l *= corr;
            #pragma unroll
            for (int i = 0; i < 16; i++) oacc[i] *= corr;
        }
        #pragma unroll
        for (int i = 0; i < 16; i++) {
            sv0[i] = __builtin_amdgcn_exp2f(sv0[i] - m);
            sv1[i] = __builtin_amdgcn_exp2f(sv1[i] - m);
        }
        // ---- row sum: v_pk_add_f32 tree + shfl partner exchange ----
        {
            #define SH2(V, I) __builtin_shufflevector(V, V, 2*(I), 2*(I)+1)
            f32x2 t0 = (SH2(sv0,0) + SH2(sv0,1)) + (SH2(sv0,2) + SH2(sv0,3));
            f32x2 t1 = (SH2(sv0,4) + SH2(sv0,5)) + (SH2(sv0,6) + SH2(sv0,7));
            f32x2 t2 = (SH2(sv1,0) + SH2(sv1,1)) + (SH2(sv1,2) + SH2(sv1,3));
            f32x2 t3 = (SH2(sv1,4) + SH2(sv1,5)) + (SH2(sv1,6) + SH2(sv1,7));
            f32x2 tt = (t0 + t1) + (t2 + t3);
            float sm = tt[0] + tt[1];
            #undef SH2
            sm += __shfl_xor(sm, 32);
            l += sm;
        }
        // ---- P->bf16 + shfl_xor(32) exchange (r5-proven form); O^T += V P ----
        #define PVSTEP(SV, BB, C) { \
            unsigned p0 = pkbf(SV[BB + 0], SV[BB + 1]); \
            unsigned p1 = pkbf(SV[BB + 2], SV[BB + 3]); \
            unsigned p2 = pkbf(SV[BB + 4], SV[BB + 5]); \
            unsigned p3 = pkbf(SV[BB + 6], SV[BB + 7]); \
            unsigned s0 = hi ? p0 : p2, s1 = hi ? p1 : p3; \
            unsigned r0 = __shfl_xor(s0, 32), r1 = __shfl_xor(s1, 32); \
            uint4 fu = hi ? make_uint4(r0, r1, p2, p3) : make_uint4(p0, p1, r0, r1); \
            short8 pa = *(short8*)&fu; \
            short8 vf = *(const short8*)&V_lds[lo32 * 64 + ((((C) * 2 + hi) ^ (lo32 & 7)) * 8)]; \
            oacc = __builtin_amdgcn_mfma_f32_32x32x16_bf16(vf, pa, oacc, 0, 0, 0); \
        }
        __builtin_amdgcn_s_setprio(1);
        PVSTEP(sv0, 0, 0)
        PVSTEP(sv0, 8, 1)
        PVSTEP(sv1, 0, 2)
        PVSTEP(sv1, 8, 3)
        __builtin_amdgcn_s_setprio(0);
        #undef PVSTEP
        __syncthreads();   // protect K_lds/V_lds before next stage
    }
    // bf16 unnormalized partials: lane q = q0+lo32, d = 8*rr + 4*hi + 0..3
    unsigned short* op = opart + ((((size_t)s * BATCH + b) * HEADS + h) * NSP + q0 + lo32) * HD;
    #pragma unroll
    for (int rr = 0; rr < 4; rr++) {
        ushort4 pk4;
        pk4.x = f2bf(oacc[rr * 4 + 0]);
        pk4.y = f2bf(oacc[rr * 4 + 1]);
        pk4.z = f2bf(oacc[rr * 4 + 2]);
        pk4.w = f2bf(oacc[rr * 4 + 3]);
        *(ushort4*)(op + rr * 8 + hi * 4) = pk4;
    }
    if (hi == 0)
        *(float2*)(lmpart + ((((size_t)s * BATCH + b) * HEADS + h) * NSP + q0 + lo32) * 2)
            = make_float2(m, l);
}

// ------------- K7: combine NSPLIT partials -> att bf16 (b,p,c) -------------
__global__ __launch_bounds__(256)
void k_combine(const unsigned short* __restrict__ opart, const float* __restrict__ lmpart,
               unsigned short* __restrict__ att) {
    int flat = blockIdx.x * 256 + threadIdx.x;   // 2*8*4096*4 = 262144
    int dchunk = flat & 3;
    int q = (flat >> 2) & (NSP - 1);
    int bh = flat >> 14;
    const size_t sO = (size_t)BATCH * HEADS * NSP * HD;
    const size_t sL = (size_t)BATCH * HEADS * NSP * 2;
    size_t rowq = (size_t)bh * NSP + q;
    float2 lm[NSPLIT];
    float M = -1e30f;
    #pragma unroll
    for (int s2 = 0; s2 < NSPLIT; s2++) {
        lm[s2] = *(const float2*)(lmpart + s2 * sL + rowq * 2);
        M = fmaxf(M, lm[s2].x);
    }
    float den = 0.f, cw[NSPLIT];
    #pragma unroll
    for (int s2 = 0; s2 < NSPLIT; s2++) {
        cw[s2] = __builtin_amdgcn_exp2f(lm[s2].x - M);
        den += lm[s2].y * cw[s2];
    }
    float inv = 1.0f / den;
    float acc[8];
    #pragma unroll
    for (int e = 0; e < 8; e++) acc[e] = 0.f;
    #pragma unroll
    for (int s2 = 0; s2 < NSPLIT; s2++) {
        uint4 v = *(const uint4*)(opart + s2 * sO + rowq * HD + dchunk * 8);
        float wgt = cw[s2] * inv;
        const unsigned short* pv = (const unsigned short*)&v;
        #pragma unroll
        for (int e = 0; e < 8; e++) {
            unsigned u = (unsigned)pv[e] << 16;
            acc[e] += wgt * *(float*)&u;
        }
    }
    uint4 o;
    o.x = (unsigned)f2bf(acc[0]) | ((unsigned)f2bf(acc[1]) << 16);
    o.y = (unsigned)f2bf(acc[2]) | ((unsigned)f2bf(acc[3]) << 16);
    o.z = (unsigned)f2bf(acc[4]) | ((unsigned)f2bf(acc[5]) << 16);
    o.w = (unsigned)f2bf(acc[6]) | ((unsigned)f2bf(acc[7]) << 16);
    *(uint4*)(att + ((size_t)((bh >> 3) * NSP + q)) * CH + (bh & 7) * HD + dchunk * 8) = o;
}

extern "C" void kernel_launch(void* const* d_in, const int* in_sizes, int n_in,
                              void* d_out, int out_size, void* d_ws, size_t ws_size,
                              hipStream_t stream) {
    const float* x       = (const float*)d_in[0];
    const float* gn_w    = (const float*)d_in[1];
    const float* gn_b    = (const float*)d_in[2];
    const float* qkv_w   = (const float*)d_in[3];
    const float* qkv_b   = (const float*)d_in[4];
    const float* proj_w  = (const float*)d_in[5];
    const float* proj_b  = (const float*)d_in[6];
    const float* gproj_w = (const float*)d_in[7];
    const float* gproj_b = (const float*)d_in[8];
    char* ws = (char*)d_ws;
    float*          stats  = (float*)(ws);                      // 512 B
    float*          gpart  = (float*)(ws + 1024);               // 128 KB
    float*          gfeat  = (float*)(ws + 132096);             // 2 KB
    unsigned short* wbf    = (unsigned short*)(ws + 134144);    // 512 KB bf16 weights
    unsigned short* xnt    = (unsigned short*)(ws + 658432);    // (b,p,c) bf16, 4 MB (dead after qkv GEMM)
    float*          lmpart = (float*)(ws + 658432);             // overlays xnt: 2 MB {m,l}
    unsigned short* qt     = (unsigned short*)(ws + 4852736);   // (b,h,n,hd) bf16, 4 MB
    unsigned short* kt     = (unsigned short*)(ws + 9047040);   // (b,h,n,hd) bf16, 4 MB
    unsigned short* vt     = (unsigned short*)(ws + 13241344);  // (b,h,hd,n) bf16, 4 MB
    unsigned short* att    = (unsigned short*)(ws + 17435648);  // (b,p,c) bf16, 4 MB
    unsigned short* opart  = (unsigned short*)(ws + 21629952);  // 4 splits bf16 O, 16.8 MB
    float* out = (float*)d_out;

    hipLaunchKernelGGL(k_gnstats, dim3(64), dim3(256), 0, stream, x, stats);
    hipLaunchKernelGGL(k_gnapply, dim3(64, 4, 2), dim3(256), 0, stream,
                       x, gn_w, gn_b, stats, xnt, gpart);
    hipLaunchKernelGGL(k_gproj, dim3(2), dim3(256), 0, stream,
                       gpart, gproj_w, gproj_b, gfeat);
    hipLaunchKernelGGL(k_convert, dim3(256), dim3(256), 0, stream, qkv_w, proj_w, wbf);
    hipLaunchKernelGGL(k_gemm_qkv, dim3(32, 12, 2), dim3(256), 0, stream,
                       wbf, xnt, qkv_b, gfeat, qt, kt, vt);
    hipLaunchKernelGGL(k_flash32, dim3(32 * NSPLIT, 8, 2), dim3(256), 0, stream,
                       qt, kt, vt, opart, lmpart);
    hipLaunchKernelGGL(k_combine, dim3(1024), dim3(256), 0, stream,
                       opart, lmpart, att);
    hipLaunchKernelGGL(k_gemm_proj, dim3(32, 4, 2), dim3(256), 0, stream,
                       wbf + 196608, att, proj_b, gfeat, x, out);
}